// Round 9
// baseline (256.427 us; speedup 1.0000x reference)
//
#include <hip/hip_runtime.h>
#include <hip/hip_bf16.h>

typedef __bf16 bf16x8 __attribute__((ext_vector_type(8)));
typedef __bf16 bf16x4 __attribute__((ext_vector_type(4)));
typedef __bf16 bf16x2 __attribute__((ext_vector_type(2)));
typedef float f32x4 __attribute__((ext_vector_type(4)));

#define HW 4096
#define DIMC 192
#define DH 48
#define HIDC 510
#define LOG2E 1.44269504088896f

// raw v_exp_f32 (2^x): skip the ocml range/denorm fixups (r5: -19us in attn).
__device__ __forceinline__ float exp2_fast(float x) {
#if __has_builtin(__builtin_amdgcn_exp2f)
  return __builtin_amdgcn_exp2f(x);
#else
  float r;
  asm("v_exp_f32 %0, %1\n\ts_nop 1" : "=v"(r) : "v"(x));
  return r;
#endif
}

__device__ __forceinline__ float rcp_fast(float x) {
#if __has_builtin(__builtin_amdgcn_rcpf)
  return __builtin_amdgcn_rcpf(x);
#else
  float r;
  asm("v_rcp_f32 %0, %1\n\ts_nop 1" : "=v"(r) : "v"(x));
  return r;
#endif
}

// gelu via A&S 7.1.26 erf (|err|<=1.5e-7) on exp2_fast+rcp_fast — no ocml call.
__device__ __forceinline__ float gelu_fast(float x) {
  float z = fabsf(x) * 0.70710678118654752f;
  float t = rcp_fast(fmaf(0.3275911f, z, 1.f));
  float p = t * fmaf(t, fmaf(t, fmaf(t, fmaf(t, 1.061405429f, -1.453152027f), 1.421413741f), -0.284496736f), 0.254829592f);
  float e = exp2_fast(-z * z * 1.4426950408889634f);
  float erfa = 1.f - p * e;          // erf(|x|/sqrt2)
  float erfx = copysignf(erfa, x);
  return 0.5f * x * (1.f + erfx);
}

// ---------------- combo: weight convert (blocks 0..1724) + LN1 stats (blocks 1725..2108) ----------------
__global__ __launch_bounds__(256) void wcvt_ln_kernel(const float* __restrict__ qkv_w, const float* __restrict__ proj_w,
                                                      const float* __restrict__ pin_w, const float* __restrict__ pout_w,
                                                      __bf16* __restrict__ wb_qkv, __bf16* __restrict__ wb_proj,
                                                      __bf16* __restrict__ wb_pin, __bf16* __restrict__ wb_pout,
                                                      const float* __restrict__ x, const float* __restrict__ lw,
                                                      const float* __restrict__ lb, float* __restrict__ sc,
                                                      float* __restrict__ sh) {
  __shared__ float red[8];
  if (blockIdx.x < 1725) {
    int idx = blockIdx.x * 256 + threadIdx.x;
    if (idx < 110592) {                       // qkv 576x192
      wb_qkv[idx] = (__bf16)qkv_w[idx];
    } else if (idx < 147456) {                // proj 192x192
      int i = idx - 110592;
      wb_proj[i] = (__bf16)proj_w[i];
    } else if (idx < 343296) {                // pin 1020x192
      int i = idx - 147456;
      wb_pin[i] = (__bf16)pin_w[i];
    } else if (idx < 441600) {                // pout 192x512 (pad c 510,511)
      int i = idx - 343296;
      int o = i >> 9, c = i & 511;
      wb_pout[i] = (c < HIDC) ? (__bf16)pout_w[o * HIDC + c] : (__bf16)0.f;
    }
    return;
  }
  int bc = blockIdx.x - 1725;     // b*DIMC + c
  int c = bc % DIMC;
  const float* row = x + (size_t)bc * HW;
  float s = 0.f, s2 = 0.f;
  for (int i = threadIdx.x * 4; i < HW; i += 1024) {
    f32x4 v = *(const f32x4*)&row[i];
    s += (v.x + v.y) + (v.z + v.w);
    s2 = fmaf(v.x, v.x, s2); s2 = fmaf(v.y, v.y, s2);
    s2 = fmaf(v.z, v.z, s2); s2 = fmaf(v.w, v.w, s2);
  }
  for (int off = 32; off; off >>= 1) { s += __shfl_down(s, off, 64); s2 += __shfl_down(s2, off, 64); }
  int wid = threadIdx.x >> 6;
  if ((threadIdx.x & 63) == 0) { red[wid] = s; red[4 + wid] = s2; }
  __syncthreads();
  if (threadIdx.x == 0) {
    s = red[0] + red[1] + red[2] + red[3];
    s2 = red[4] + red[5] + red[6] + red[7];
    float mean = s * (1.f / HW);
    float var = s2 * (1.f / HW) - mean * mean;
    float rstd = rsqrtf(var + 1e-6f);
    float scv = rstd * lw[c];
    sc[bc] = scv;
    sh[bc] = lb[c] - mean * scv;
  }
}

// ---------------- LN stats (standalone, phase B) ----------------
__global__ __launch_bounds__(256) void ln_stats_kernel(const float* __restrict__ x, const float* __restrict__ w,
                                                       const float* __restrict__ b, float* __restrict__ sc,
                                                       float* __restrict__ sh) {
  int bc = blockIdx.x;            // b*DIMC + c
  int c = bc % DIMC;
  const float* row = x + (size_t)bc * HW;
  float s = 0.f, s2 = 0.f;
  for (int i = threadIdx.x * 4; i < HW; i += 1024) {
    f32x4 v = *(const f32x4*)&row[i];
    s += (v.x + v.y) + (v.z + v.w);
    s2 = fmaf(v.x, v.x, s2); s2 = fmaf(v.y, v.y, s2);
    s2 = fmaf(v.z, v.z, s2); s2 = fmaf(v.w, v.w, s2);
  }
  __shared__ float red[8];
  for (int off = 32; off; off >>= 1) { s += __shfl_down(s, off, 64); s2 += __shfl_down(s2, off, 64); }
  int wid = threadIdx.x >> 6;
  if ((threadIdx.x & 63) == 0) { red[wid] = s; red[4 + wid] = s2; }
  __syncthreads();
  if (threadIdx.x == 0) {
    s = red[0] + red[1] + red[2] + red[3];
    s2 = red[4] + red[5] + red[6] + red[7];
    float mean = s * (1.f / HW);
    float var = s2 * (1.f / HW) - mean * mean;
    float rstd = rsqrtf(var + 1e-6f);
    float scv = rstd * w[c];
    sc[bc] = scv;
    sh[bc] = b[c] - mean * scv;
  }
}

// ---------------- bf16 MFMA GEMM, K-step 64 ----------------
// mode 0: fp32 out; 1: bf16 out; 2: fp32 out + fp32 residual;
// mode 3: +res, B = bf16 gate [b][510][n] transposed+padded on the fly (Cs must be 512);
// mode 4: +res, B = attention partials `part` (2-chunk merge + linv normalize on the fly);
// mode 5: bf16 out, B = LN(xf) transposed on the fly (xf fp32 [b][192][n], sc/sh per (b,c)).
__global__ __launch_bounds__(256) void gemm_kernel(const __bf16* __restrict__ A, const __bf16* __restrict__ Bt,
                                                   const float* __restrict__ bias, const float* __restrict__ res,
                                                   float* __restrict__ outf, __bf16* __restrict__ outb,
                                                   const float* __restrict__ part,
                                                   const float* __restrict__ scp, const float* __restrict__ shp,
                                                   int O, int Cs, int mode) {
  __shared__ __align__(16) __bf16 Asub[64 * 72];
  __shared__ __align__(16) __bf16 Bsub[128 * 72];
  __shared__ float linvS[4][128];
  const int t = threadIdx.x;
  const int lane = t & 63, wv = t >> 6;
  const int q4 = lane >> 4, l16 = lane & 15;
  int o0 = blockIdx.y * 64;
  if (o0 + 64 > O) o0 = O - 64;
  const int ntot0 = blockIdx.x * 128;
  const int b = ntot0 >> 12;
  const int n_in_b0 = ntot0 & 4095;

  if (mode == 4) {
    // per-(head, n) 1/l for this block's 128 n rows
#pragma unroll
    for (int jj = 0; jj < 2; ++jj) {
      int id = t + 256 * jj;
      int h = id >> 7, nl = id & 127;
      int n_in_b = n_in_b0 + nl;
      int ntb = n_in_b >> 6, n64 = n_in_b & 63;
      size_t pb = ((size_t)((b * 4 + h) * 64 + ntb)) * 3136 + 3072 + n64;
      float s = part[pb] + part[pb + (size_t)512 * 3136];
      linvS[h][nl] = rcp_fast(s);
    }
  }

  f32x4 acc[8];
#pragma unroll
  for (int nt = 0; nt < 8; ++nt) acc[nt] = (f32x4){0.f, 0.f, 0.f, 0.f};

  for (int c0 = 0; c0 < Cs; c0 += 64) {
    __syncthreads();
#pragma unroll
    for (int j = 0; j < 2; ++j) {           // A: 64 rows x 64 c
      int id = t + 256 * j;
      *(bf16x8*)&Asub[(id >> 3) * 72 + (id & 7) * 8] =
          *(const bf16x8*)&A[((size_t)(o0 + (id >> 3))) * Cs + c0 + (id & 7) * 8];
    }
    if (mode == 4) {
      // B from attention partials: B[n][c] = (part_ch0 + part_ch1) * linv, c = h*48+cc
#pragma unroll
      for (int j = 0; j < 4; ++j) {
        int id = t + 256 * j;
        int row = id >> 3, cgrp = id & 7;
        int cglob = c0 + cgrp * 8;
        int h = cglob / 48;
        int cc = cglob - h * 48;
        int n_in_b = n_in_b0 + row;
        int ntb = n_in_b >> 6, n64 = n_in_b & 63;
        size_t pb = ((size_t)((b * 4 + h) * 64 + ntb)) * 3136 + (size_t)n64 * 48 + cc;
        f32x4 a0 = *(const f32x4*)&part[pb];
        f32x4 a1 = *(const f32x4*)&part[pb + 4];
        f32x4 b0 = *(const f32x4*)&part[pb + (size_t)512 * 3136];
        f32x4 b1 = *(const f32x4*)&part[pb + (size_t)512 * 3136 + 4];
        float li = linvS[h][row];
        f32x4 s0 = (a0 + b0) * li;
        f32x4 s1 = (a1 + b1) * li;
        bf16x8 ov = { (__bf16)s0.x, (__bf16)s0.y, (__bf16)s0.z, (__bf16)s0.w,
                      (__bf16)s1.x, (__bf16)s1.y, (__bf16)s1.z, (__bf16)s1.w };
        *(bf16x8*)&Bsub[row * 72 + cgrp * 8] = ov;
      }
    } else if (mode == 5) {
      // B = LN(xf): thread covers c-row (t&63), 32-n segment (t>>6); fp32 source, fused scale+shift
      int cr = t & 63, seg = t >> 6;
      int cglob = c0 + cr;                    // Cs==192, always valid
      const float* xp = part + ((size_t)(b * DIMC + cglob)) * HW + n_in_b0 + seg * 32;
      float scv = scp[b * DIMC + cglob], shv = shp[b * DIMC + cglob];
      float rr[32];
#pragma unroll
      for (int q = 0; q < 8; ++q) *(f32x4*)&rr[4 * q] = *(const f32x4*)&xp[4 * q];
#pragma unroll
      for (int k = 0; k < 32; ++k) Bsub[(seg * 32 + k) * 72 + cr] = (__bf16)fmaf(rr[k], scv, shv);
    } else if (mode != 3) {
#pragma unroll
      for (int j = 0; j < 4; ++j) {         // B: 128 rows x 64 c from [n][c] layout
        int id = t + 256 * j;
        *(bf16x8*)&Bsub[(id >> 3) * 72 + (id & 7) * 8] =
            *(const bf16x8*)&Bt[((size_t)(ntot0 + (id >> 3))) * Cs + c0 + (id & 7) * 8];
      }
    } else {
      // transposing stage from gate [b][510][n]: thread t covers c-row (t&63), 32-n segment (t>>6)
      int cr = t & 63, seg = t >> 6;
      int cg = c0 + cr;
      __bf16 tmp[32];
      if (cg < HIDC) {
        const __bf16* gp = Bt + ((size_t)(b * HIDC + cg)) * HW + n_in_b0 + seg * 32;
#pragma unroll
        for (int j = 0; j < 4; ++j) *(bf16x8*)&tmp[8 * j] = *(const bf16x8*)&gp[8 * j];
      } else {
#pragma unroll
        for (int k = 0; k < 32; ++k) tmp[k] = (__bf16)0.f;
      }
#pragma unroll
      for (int k = 0; k < 32; ++k) Bsub[(seg * 32 + k) * 72 + cr] = tmp[k];
    }
    __syncthreads();
#pragma unroll
    for (int ks = 0; ks < 2; ++ks) {
      bf16x8 af = *(const bf16x8*)&Asub[(16 * wv + l16) * 72 + 32 * ks + 8 * q4];
#pragma unroll
      for (int nt = 0; nt < 8; ++nt) {
        bf16x8 bfr = *(const bf16x8*)&Bsub[(16 * nt + l16) * 72 + 32 * ks + 8 * q4];
        acc[nt] = __builtin_amdgcn_mfma_f32_16x16x32_bf16(af, bfr, acc[nt], 0, 0, 0);
      }
    }
  }

  float bvals[4];
#pragma unroll
  for (int r = 0; r < 4; ++r) bvals[r] = bias[o0 + 16 * wv + 4 * q4 + r];
#pragma unroll
  for (int nt = 0; nt < 8; ++nt) {
    int n_in_b = n_in_b0 + 16 * nt + l16;
#pragma unroll
    for (int r = 0; r < 4; ++r) {
      int o = o0 + 16 * wv + 4 * q4 + r;
      size_t addr = ((size_t)(b * O + o)) * HW + n_in_b;
      float v = acc[nt][r] + bvals[r];
      if (mode >= 2 && mode <= 4) { outf[addr] = v + res[addr]; }
      else if (mode == 0) { outf[addr] = v; }
      else { outb[addr] = (__bf16)v; }
    }
  }
}

// ---------------- depthwise 3x3 on bf16 qkv; q,k -> qdwb bf16; v -> Vbf bf16 [bh][c][n] ----------------
__global__ __launch_bounds__(256) void dwconv_split_kernel(const __bf16* __restrict__ in, const float* __restrict__ w,
                                                           const float* __restrict__ bias,
                                                           __bf16* __restrict__ qdwb, __bf16* __restrict__ Vbf) {
  int bc = blockIdx.x;
  int b = bc / 576, ch = bc - b * 576;
  __shared__ float tile[66 * 68];
  for (int i = threadIdx.x; i < 66 * 68; i += 256) tile[i] = 0.f;
  __syncthreads();
  const __bf16* p = in + (size_t)bc * HW;
  for (int j = 0; j < 8; ++j) {
    int i = 2 * threadIdx.x + 512 * j;
    bf16x2 v = *(const bf16x2*)&p[i];
    int y = i >> 6, xx = i & 63;
    tile[(y + 1) * 68 + xx + 1] = (float)v.x;
    tile[(y + 1) * 68 + xx + 2] = (float)v.y;
  }
  __syncthreads();
  float w0 = w[ch * 9 + 0], w1 = w[ch * 9 + 1], w2 = w[ch * 9 + 2];
  float w3 = w[ch * 9 + 3], w4 = w[ch * 9 + 4], w5 = w[ch * 9 + 5];
  float w6 = w[ch * 9 + 6], w7 = w[ch * 9 + 7], w8 = w[ch * 9 + 8];
  float bb = bias[ch];
  __bf16* dst;
  if (ch < 384) dst = qdwb + ((size_t)(b * 384 + ch)) * HW;
  else {
    int c = ch - 384, h = c / DH, cc = c - h * DH;
    dst = Vbf + ((size_t)((b * 4 + h) * DH + cc)) * HW;
  }
  for (int j = 0; j < 8; ++j) {
    int i = 2 * threadIdx.x + 512 * j;
    int y = i >> 6, xx = i & 63;
    const float* tt = &tile[y * 68 + xx];
    float a = bb;
    a = fmaf(w0, tt[0], a);   a = fmaf(w1, tt[1], a);   a = fmaf(w2, tt[2], a);
    a = fmaf(w3, tt[68], a);  a = fmaf(w4, tt[69], a);  a = fmaf(w5, tt[70], a);
    a = fmaf(w6, tt[136], a); a = fmaf(w7, tt[137], a); a = fmaf(w8, tt[138], a);
    float a2 = bb;
    a2 = fmaf(w0, tt[1], a2);   a2 = fmaf(w1, tt[2], a2);   a2 = fmaf(w2, tt[3], a2);
    a2 = fmaf(w3, tt[69], a2);  a2 = fmaf(w4, tt[70], a2);  a2 = fmaf(w5, tt[71], a2);
    a2 = fmaf(w6, tt[137], a2); a2 = fmaf(w7, tt[138], a2); a2 = fmaf(w8, tt[139], a2);
    bf16x2 o = { (__bf16)a, (__bf16)a2 };
    *(bf16x2*)&dst[i] = o;
  }
}

// ---------------- GDFN v2: strip compute (1x16 px/thread, b128 LDS reads) + fast gelu ----------------
__global__ __launch_bounds__(256) void gdfn_dw_gate_kernel(const __bf16* __restrict__ hid, const float* __restrict__ w,
                                                           const float* __restrict__ bias, __bf16* __restrict__ gate) {
  int blk = blockIdx.x;           // b*HIDC + j
  int b = blk / HIDC, j = blk - b * HIDC;
  __shared__ __align__(16) float t1[66 * 68];
  __shared__ __align__(16) float t2[66 * 68];
  const int tid = threadIdx.x;
  // halo-only zero init: rows 0 and 65 (all 68 cols), cols {0,65,66,67} for rows 1..64
  if (tid < 136) {
    int r = (tid >= 68) ? 65 : 0;
    int c = (tid >= 68) ? tid - 68 : tid;
    t1[r * 68 + c] = 0.f;
    t2[r * 68 + c] = 0.f;
  }
  {
    int r = (tid >> 2) + 1;
    int c4 = tid & 3;
    int c = (c4 == 0) ? 0 : 64 + c4;   // 0,65,66,67
    t1[r * 68 + c] = 0.f;
    t2[r * 68 + c] = 0.f;
  }
  const __bf16* p1 = hid + ((size_t)b * (2 * HIDC) + j) * HW;
  const __bf16* p2 = p1 + (size_t)HIDC * HW;
  for (int jj = 0; jj < 8; ++jj) {
    int i = 2 * tid + 512 * jj;
    bf16x2 v1 = *(const bf16x2*)&p1[i];
    bf16x2 v2 = *(const bf16x2*)&p2[i];
    int y = i >> 6, xx = i & 63;
    t1[(y + 1) * 68 + xx + 1] = (float)v1.x;
    t1[(y + 1) * 68 + xx + 2] = (float)v1.y;
    t2[(y + 1) * 68 + xx + 1] = (float)v2.x;
    t2[(y + 1) * 68 + xx + 2] = (float)v2.y;
  }
  __syncthreads();
  int c1 = j, c2 = j + HIDC;
  float wa[9], wb[9];
#pragma unroll
  for (int k = 0; k < 9; ++k) { wa[k] = w[c1 * 9 + k]; wb[k] = w[c2 * 9 + k]; }
  float bi1 = bias[c1], bi2 = bias[c2];

  const int y = tid >> 2, x0 = 16 * (tid & 3);
  float x1v[16], x2v[16];
#pragma unroll
  for (int p = 0; p < 16; ++p) { x1v[p] = bi1; x2v[p] = bi2; }
#pragma unroll
  for (int r = 0; r < 3; ++r) {
    const float* rp1 = &t1[(y + r) * 68 + x0];
    float rr[20];
#pragma unroll
    for (int q = 0; q < 5; ++q) *(f32x4*)&rr[4 * q] = *(const f32x4*)&rp1[4 * q];
    float w0 = wa[3 * r], w1 = wa[3 * r + 1], w2 = wa[3 * r + 2];
#pragma unroll
    for (int p = 0; p < 16; ++p)
      x1v[p] = fmaf(w0, rr[p], fmaf(w1, rr[p + 1], fmaf(w2, rr[p + 2], x1v[p])));
  }
#pragma unroll
  for (int r = 0; r < 3; ++r) {
    const float* rp2 = &t2[(y + r) * 68 + x0];
    float rr[20];
#pragma unroll
    for (int q = 0; q < 5; ++q) *(f32x4*)&rr[4 * q] = *(const f32x4*)&rp2[4 * q];
    float w0 = wb[3 * r], w1 = wb[3 * r + 1], w2 = wb[3 * r + 2];
#pragma unroll
    for (int p = 0; p < 16; ++p)
      x2v[p] = fmaf(w0, rr[p], fmaf(w1, rr[p + 1], fmaf(w2, rr[p + 2], x2v[p])));
  }
  __bf16 ob[16];
#pragma unroll
  for (int p = 0; p < 16; ++p) ob[p] = (__bf16)(gelu_fast(x1v[p]) * x2v[p]);
  __bf16* op = gate + ((size_t)b * HIDC + j) * HW + y * 64 + x0;
  *(bf16x8*)&op[0] = *(bf16x8*)&ob[0];
  *(bf16x8*)&op[8] = *(bf16x8*)&ob[8];
}

// ---------------- prep (1-wide, q/k split over blockIdx.y): normalize; fold temp*log2e into q ----------------
// grid (128, 2): 2x the TLP of the 2-wide version (was 0.5 blocks/CU — latency-starved).
__global__ __launch_bounds__(256) void prep_qk_kernel(const __bf16* __restrict__ qdwb, const float* __restrict__ temp,
                                                      __bf16* __restrict__ Qbf, __bf16* __restrict__ Kbf) {
  int t2 = blockIdx.x * 256 + threadIdx.x;   // 0..32767
  int bh = t2 >> 12;
  int np = t2 & 4095;
  int b = bh >> 2, h = bh & 3;
  const int isK = blockIdx.y;
  const __bf16* sp = qdwb + ((size_t)(b * 384 + isK * 192 + h * DH)) * HW + np;
  float tq = isK ? 1.f : temp[h] * LOG2E;

  __bf16 raw[DH];
  float ss = 0.f;
#pragma unroll
  for (int c = 0; c < DH; ++c) {
    __bf16 v = sp[(size_t)c * HW];
    raw[c] = v;
    float f = (float)v;
    ss = fmaf(f, f, ss);
  }
  float scv = tq / fmaxf(sqrtf(ss), 1e-12f);
  __bf16 ob[64];
#pragma unroll
  for (int c = 0; c < DH; ++c) ob[c] = (__bf16)((float)raw[c] * scv);
#pragma unroll
  for (int c = DH; c < 64; ++c) ob[c] = (__bf16)0.f;
  __bf16* dd = (isK ? Kbf : Qbf) + ((size_t)(bh << 12) + np) * 64;
#pragma unroll
  for (int ch = 0; ch < 8; ++ch) *(bf16x8*)&dd[ch * 8] = *(bf16x8*)&ob[ch * 8];
}

// ---------------- flash attention split-K v10: K-direct regs + dbuf LDS, 1 barrier/iter, ptr-bump ----------------
// grid 1024 = chunk*512 + bh*64 + nt; block 256 (4 waves).
__global__ __launch_bounds__(256) void attn_split_kernel(const __bf16* __restrict__ Qbf, const __bf16* __restrict__ Kbf,
                                                         const __bf16* __restrict__ Vbf, float* __restrict__ part) {
  __shared__ __align__(16) __bf16 Vc[2][48 * 72];   // Vc[buf][c][m]
  __shared__ __align__(16) __bf16 Pl[2][64 * 72];   // Pl[buf][n][m] (Pl[0] reused as Lred in epilogue)
  const int tid = threadIdx.x;
  const int lane = tid & 63;
  const int wv = tid >> 6;
  const int q4 = lane >> 4, l16 = lane & 15;
  const int bid = blockIdx.x;
  const int chunk = bid >> 9, rest = bid & 511;
  const int bh = rest >> 6, nt = rest & 63;
  const int n0 = nt * 64;
  const __bf16* Qg = Qbf + (size_t)bh * HW * 64;
  const __bf16* Kg = Kbf + (size_t)bh * HW * 64;
  const __bf16* Vg = Vbf + (size_t)bh * DH * HW;

  // Q fragments in registers (B-operand of S^T): qf[s][ks] = Q[n0+16s+l16][32ks+8q4 ..+7]
  bf16x8 qf[4][2];
#pragma unroll
  for (int s = 0; s < 4; ++s)
#pragma unroll
    for (int ks = 0; ks < 2; ++ks)
      qf[s][ks] = *(const bf16x8*)&Qg[((size_t)(n0 + 16 * s + l16)) * 64 + 32 * ks + 8 * q4];

  // K fragment pointers (per-wave rows) and V staging pointers; bump by one m-tile per iter.
  const int m0 = chunk * 2048;   // 32 m-tiles * 64
  const __bf16* kp0 = Kg + ((size_t)(m0 + 16 * wv + l16)) * 64 + 8 * q4;
  const __bf16* kp1 = kp0 + 32;
  const __bf16* vp0 = Vg + ((size_t)(tid >> 3)) * HW + m0 + (tid & 7) * 8;
  const __bf16* vp1 = Vg + ((size_t)((tid + 256) >> 3)) * HW + m0 + ((tid + 256) & 7) * 8;
  bf16x8 kf0 = *(const bf16x8*)kp0;
  bf16x8 kf1 = *(const bf16x8*)kp1;
  bf16x8 vreg[2];
  vreg[0] = *(const bf16x8*)vp0;
  if (tid < 128) vreg[1] = *(const bf16x8*)vp1;

  float lsub[4] = {0.f, 0.f, 0.f, 0.f};
  f32x4 oacc[3];
#pragma unroll
  for (int ct = 0; ct < 3; ++ct) oacc[ct] = (f32x4){0.f, 0.f, 0.f, 0.f};

  for (int it = 0; it < 32; ++it) {
    const int cur = it & 1;
    // write prefetched V regs -> LDS buffer `cur` (prior PV readers used buffer cur^1)
    *(bf16x8*)&Vc[cur][(tid >> 3) * 72 + (tid & 7) * 8] = vreg[0];
    if (tid < 128) {
      int i = tid + 256;
      *(bf16x8*)&Vc[cur][(i >> 3) * 72 + (i & 7) * 8] = vreg[1];
    }
    // issue next iteration's global loads (pointer bumps; final-iter over-read stays in workspace, unused)
    kp0 += 4096; kp1 += 4096; vp0 += 64; vp1 += 64;
    bf16x8 kn0 = *(const bf16x8*)kp0;
    bf16x8 kn1 = *(const bf16x8*)kp1;
    vreg[0] = *(const bf16x8*)vp0;
    if (tid < 128) vreg[1] = *(const bf16x8*)vp1;

    // S^T[m][n] = K·Q^T: pure-register MFMA
    f32x4 sacc[4];
#pragma unroll
    for (int s = 0; s < 4; ++s) sacc[s] = (f32x4){0.f, 0.f, 0.f, 0.f};
    __builtin_amdgcn_s_setprio(1);
#pragma unroll
    for (int s = 0; s < 4; ++s)
      sacc[s] = __builtin_amdgcn_mfma_f32_16x16x32_bf16(kf0, qf[s][0], sacc[s], 0, 0, 0);
#pragma unroll
    for (int s = 0; s < 4; ++s)
      sacc[s] = __builtin_amdgcn_mfma_f32_16x16x32_bf16(kf1, qf[s][1], sacc[s], 0, 0, 0);
    __builtin_amdgcn_s_setprio(0);

    // maxless softmax (log2e pre-folded into Q); raw v_exp; packed b64 P writes (m-contig)
#pragma unroll
    for (int s = 0; s < 4; ++s) {
      float p0 = exp2_fast(sacc[s][0]);
      float p1 = exp2_fast(sacc[s][1]);
      float p2 = exp2_fast(sacc[s][2]);
      float p3 = exp2_fast(sacc[s][3]);
      lsub[s] += (p0 + p1) + (p2 + p3);
      bf16x4 pk = { (__bf16)p0, (__bf16)p1, (__bf16)p2, (__bf16)p3 };
      *(bf16x4*)&Pl[cur][(16 * s + l16) * 72 + 16 * wv + 4 * q4] = pk;
    }
    __syncthreads();                     // publish Vc[cur] + Pl[cur] (the ONLY barrier per iter)

    // O[n][c] += P·V^T: wave owns n-strip 16wv
    __builtin_amdgcn_s_setprio(1);
#pragma unroll
    for (int ks = 0; ks < 2; ++ks) {
      bf16x8 pf = *(const bf16x8*)&Pl[cur][(16 * wv + l16) * 72 + 32 * ks + 8 * q4];
#pragma unroll
      for (int ct = 0; ct < 3; ++ct) {
        bf16x8 vf = *(const bf16x8*)&Vc[cur][(16 * ct + l16) * 72 + 32 * ks + 8 * q4];
        oacc[ct] = __builtin_amdgcn_mfma_f32_16x16x32_bf16(pf, vf, oacc[ct], 0, 0, 0);
      }
    }
    __builtin_amdgcn_s_setprio(0);
    kf0 = kn0; kf1 = kn1;
  }

  // epilogue
  __syncthreads();
  float* Lred = (float*)&Pl[0][0];
#pragma unroll
  for (int s = 0; s < 4; ++s) {
    float v = lsub[s];
    v += __shfl_xor(v, 16, 64);
    v += __shfl_xor(v, 32, 64);
    if (q4 == 0) Lred[wv * 64 + 16 * s + l16] = v;
  }
  __syncthreads();
  size_t pbase = (size_t)bid * 3136;
  if (tid < 64)
    part[pbase + 3072 + tid] = Lred[tid] + Lred[64 + tid] + Lred[128 + tid] + Lred[192 + tid];
#pragma unroll
  for (int ct = 0; ct < 3; ++ct)
#pragma unroll
    for (int r = 0; r < 4; ++r) {
      int n = 16 * wv + 4 * q4 + r;
      part[pbase + (size_t)n * 48 + 16 * ct + l16] = oacc[ct][r];
    }
}

extern "C" void kernel_launch(void* const* d_in, const int* in_sizes, int n_in,
                              void* d_out, int out_size, void* d_ws, size_t ws_size,
                              hipStream_t stream) {
  const float* x        = (const float*)d_in[0];
  const float* ln1_w    = (const float*)d_in[1];
  const float* ln1_b    = (const float*)d_in[2];
  const float* qkv_w    = (const float*)d_in[3];
  const float* qkv_b    = (const float*)d_in[4];
  const float* qkv_dw_w = (const float*)d_in[5];
  const float* qkv_dw_b = (const float*)d_in[6];
  const float* temperature = (const float*)d_in[7];
  const float* proj_w   = (const float*)d_in[8];
  const float* proj_b   = (const float*)d_in[9];
  const float* ln2_w    = (const float*)d_in[10];
  const float* ln2_b    = (const float*)d_in[11];
  const float* pin_w    = (const float*)d_in[12];
  const float* pin_b    = (const float*)d_in[13];
  const float* gdfn_dw_w = (const float*)d_in[14];
  const float* gdfn_dw_b = (const float*)d_in[15];
  const float* pout_w   = (const float*)d_in[16];
  const float* pout_b   = (const float*)d_in[17];
  float* out = (float*)d_out;
  float* ws = (float*)d_ws;

  // ---- workspace layout (float offsets) ----
  __bf16* wb_qkv  = (__bf16*)(ws + 0);          // 55296 f
  __bf16* wb_proj = (__bf16*)(ws + 55296);      // 18432 f
  __bf16* wb_pin  = (__bf16*)(ws + 73728);      // 97920 f
  __bf16* wb_pout = (__bf16*)(ws + 171648);     // 49152 f
  float* sc1 = ws + 220800;
  float* sh1 = ws + 221184;
  float* sc2 = ws + 221568;
  float* sh2 = ws + 221952;                     // ends 222336
  // region B @222336: Q/K/V bf16
  __bf16* Qbf = (__bf16*)(ws + 222336);         // 1,048,576 f
  __bf16* Kbf = (__bf16*)(ws + 1270912);        // 1,048,576 f
  __bf16* Vbf = (__bf16*)(ws + 2319488);        // 786,432 f -> ends 3,105,920
  // region C @3,105,920: qkvb bf16 -> later hid
  __bf16* qkvb   = (__bf16*)(ws + 3105920);
  __bf16* hid    = (__bf16*)(ws + 3105920);     // ends 7,283,840
  // region D @5,465,216: qdwb (dead before attn) then Opart (1024 blocks)
  __bf16* qdwb  = (__bf16*)(ws + 5465216);
  float*  Opart = ws + 5465216;                 // 1024*3136 = 3,211,264 f -> ends 8,676,480
  __bf16* gate  = (__bf16*)(ws + 7283840);      // 2,088,960 f (phase B, Opart dead)
  // total 11,887,744 f = 47.6 MB

  // ---- phase A ----
  wcvt_ln_kernel<<<1725 + 2 * DIMC, 256, 0, stream>>>(qkv_w, proj_w, pin_w, pout_w,
                                                      wb_qkv, wb_proj, wb_pin, wb_pout,
                                                      x, ln1_w, ln1_b, sc1, sh1);
  gemm_kernel<<<dim3(64, 9), 256, 0, stream>>>(wb_qkv, nullptr, qkv_b, nullptr, nullptr, qkvb,
                                               x, sc1, sh1, 576, 192, 5);
  dwconv_split_kernel<<<1152, 256, 0, stream>>>(qkvb, qkv_dw_w, qkv_dw_b, qdwb, Vbf);
  prep_qk_kernel<<<dim3(128, 2), 256, 0, stream>>>(qdwb, temperature, Qbf, Kbf);
  attn_split_kernel<<<1024, 256, 0, stream>>>(Qbf, Kbf, Vbf, Opart);
  gemm_kernel<<<dim3(64, 3), 256, 0, stream>>>(wb_proj, nullptr, proj_b, x, out, nullptr,
                                               Opart, nullptr, nullptr, 192, 192, 4);

  // ---- phase B ----
  ln_stats_kernel<<<2 * DIMC, 256, 0, stream>>>(out, ln2_w, ln2_b, sc2, sh2);
  gemm_kernel<<<dim3(64, 16), 256, 0, stream>>>(wb_pin, nullptr, pin_b, nullptr, nullptr, hid,
                                                out, sc2, sh2, 1020, 192, 5);
  gdfn_dw_gate_kernel<<<2 * HIDC, 256, 0, stream>>>(hid, gdfn_dw_w, gdfn_dw_b, gate);
  gemm_kernel<<<dim3(64, 3), 256, 0, stream>>>(wb_pout, (const __bf16*)gate, pout_b, out, out, nullptr,
                                               nullptr, nullptr, nullptr, 192, 512, 3);
}

// Round 10
// 238.859 us; speedup vs baseline: 1.0735x; 1.0735x over previous
//
#include <hip/hip_runtime.h>
#include <hip/hip_bf16.h>

typedef __bf16 bf16x8 __attribute__((ext_vector_type(8)));
typedef __bf16 bf16x4 __attribute__((ext_vector_type(4)));
typedef __bf16 bf16x2 __attribute__((ext_vector_type(2)));
typedef float f32x4 __attribute__((ext_vector_type(4)));

#define HW 4096
#define DIMC 192
#define DH 48
#define HIDC 510
#define LOG2E 1.44269504088896f

// raw v_exp_f32 (2^x): skip the ocml range/denorm fixups (r5: -19us in attn).
__device__ __forceinline__ float exp2_fast(float x) {
#if __has_builtin(__builtin_amdgcn_exp2f)
  return __builtin_amdgcn_exp2f(x);
#else
  float r;
  asm("v_exp_f32 %0, %1\n\ts_nop 1" : "=v"(r) : "v"(x));
  return r;
#endif
}

__device__ __forceinline__ float rcp_fast(float x) {
#if __has_builtin(__builtin_amdgcn_rcpf)
  return __builtin_amdgcn_rcpf(x);
#else
  float r;
  asm("v_rcp_f32 %0, %1\n\ts_nop 1" : "=v"(r) : "v"(x));
  return r;
#endif
}

// gelu via A&S 7.1.26 erf (|err|<=1.5e-7) on exp2_fast+rcp_fast — no ocml call.
__device__ __forceinline__ float gelu_fast(float x) {
  float z = fabsf(x) * 0.70710678118654752f;
  float t = rcp_fast(fmaf(0.3275911f, z, 1.f));
  float p = t * fmaf(t, fmaf(t, fmaf(t, fmaf(t, 1.061405429f, -1.453152027f), 1.421413741f), -0.284496736f), 0.254829592f);
  float e = exp2_fast(-z * z * 1.4426950408889634f);
  float erfa = 1.f - p * e;          // erf(|x|/sqrt2)
  float erfx = copysignf(erfa, x);
  return 0.5f * x * (1.f + erfx);
}

// ---------------- combo: weight convert (blocks 0..1724) + LN1 stats (blocks 1725..2108) ----------------
__global__ __launch_bounds__(256) void wcvt_ln_kernel(const float* __restrict__ qkv_w, const float* __restrict__ proj_w,
                                                      const float* __restrict__ pin_w, const float* __restrict__ pout_w,
                                                      __bf16* __restrict__ wb_qkv, __bf16* __restrict__ wb_proj,
                                                      __bf16* __restrict__ wb_pin, __bf16* __restrict__ wb_pout,
                                                      const float* __restrict__ x, const float* __restrict__ lw,
                                                      const float* __restrict__ lb, float* __restrict__ sc,
                                                      float* __restrict__ sh) {
  __shared__ float red[8];
  if (blockIdx.x < 1725) {
    int idx = blockIdx.x * 256 + threadIdx.x;
    if (idx < 110592) {                       // qkv 576x192
      wb_qkv[idx] = (__bf16)qkv_w[idx];
    } else if (idx < 147456) {                // proj 192x192
      int i = idx - 110592;
      wb_proj[i] = (__bf16)proj_w[i];
    } else if (idx < 343296) {                // pin 1020x192
      int i = idx - 147456;
      wb_pin[i] = (__bf16)pin_w[i];
    } else if (idx < 441600) {                // pout 192x512 (pad c 510,511)
      int i = idx - 343296;
      int o = i >> 9, c = i & 511;
      wb_pout[i] = (c < HIDC) ? (__bf16)pout_w[o * HIDC + c] : (__bf16)0.f;
    }
    return;
  }
  int bc = blockIdx.x - 1725;     // b*DIMC + c
  int c = bc % DIMC;
  const float* row = x + (size_t)bc * HW;
  float s = 0.f, s2 = 0.f;
  for (int i = threadIdx.x * 4; i < HW; i += 1024) {
    f32x4 v = *(const f32x4*)&row[i];
    s += (v.x + v.y) + (v.z + v.w);
    s2 = fmaf(v.x, v.x, s2); s2 = fmaf(v.y, v.y, s2);
    s2 = fmaf(v.z, v.z, s2); s2 = fmaf(v.w, v.w, s2);
  }
  for (int off = 32; off; off >>= 1) { s += __shfl_down(s, off, 64); s2 += __shfl_down(s2, off, 64); }
  int wid = threadIdx.x >> 6;
  if ((threadIdx.x & 63) == 0) { red[wid] = s; red[4 + wid] = s2; }
  __syncthreads();
  if (threadIdx.x == 0) {
    s = red[0] + red[1] + red[2] + red[3];
    s2 = red[4] + red[5] + red[6] + red[7];
    float mean = s * (1.f / HW);
    float var = s2 * (1.f / HW) - mean * mean;
    float rstd = rsqrtf(var + 1e-6f);
    float scv = rstd * lw[c];
    sc[bc] = scv;
    sh[bc] = lb[c] - mean * scv;
  }
}

// ---------------- LN stats (standalone, phase B) ----------------
__global__ __launch_bounds__(256) void ln_stats_kernel(const float* __restrict__ x, const float* __restrict__ w,
                                                       const float* __restrict__ b, float* __restrict__ sc,
                                                       float* __restrict__ sh) {
  int bc = blockIdx.x;            // b*DIMC + c
  int c = bc % DIMC;
  const float* row = x + (size_t)bc * HW;
  float s = 0.f, s2 = 0.f;
  for (int i = threadIdx.x * 4; i < HW; i += 1024) {
    f32x4 v = *(const f32x4*)&row[i];
    s += (v.x + v.y) + (v.z + v.w);
    s2 = fmaf(v.x, v.x, s2); s2 = fmaf(v.y, v.y, s2);
    s2 = fmaf(v.z, v.z, s2); s2 = fmaf(v.w, v.w, s2);
  }
  __shared__ float red[8];
  for (int off = 32; off; off >>= 1) { s += __shfl_down(s, off, 64); s2 += __shfl_down(s2, off, 64); }
  int wid = threadIdx.x >> 6;
  if ((threadIdx.x & 63) == 0) { red[wid] = s; red[4 + wid] = s2; }
  __syncthreads();
  if (threadIdx.x == 0) {
    s = red[0] + red[1] + red[2] + red[3];
    s2 = red[4] + red[5] + red[6] + red[7];
    float mean = s * (1.f / HW);
    float var = s2 * (1.f / HW) - mean * mean;
    float rstd = rsqrtf(var + 1e-6f);
    float scv = rstd * w[c];
    sc[bc] = scv;
    sh[bc] = b[c] - mean * scv;
  }
}

// ---------------- LN apply + transpose-convert: fp32 [b][192][n] -> bf16 Xt[(b*4096+n)][192] ----------------
__global__ __launch_bounds__(256) void ln_apply_t_kernel(const float* __restrict__ x, const float* __restrict__ sc,
                                                         const float* __restrict__ sh, __bf16* __restrict__ Xt) {
  int n0 = blockIdx.x * 64, c0 = blockIdx.y * 32, b = blockIdx.z;
  int t = threadIdx.x;
  int n = t & 63, cs = c0 + (t >> 6) * 8;
  __bf16 ob[8];
#pragma unroll
  for (int cc = 0; cc < 8; ++cc) {
    int c = cs + cc;
    float v = fmaf(x[((size_t)(b * DIMC + c)) * HW + n0 + n], sc[b * DIMC + c], sh[b * DIMC + c]);
    ob[cc] = (__bf16)v;
  }
  *(bf16x8*)&Xt[((size_t)((b << 12) + n0 + n)) * DIMC + cs] = *(bf16x8*)ob;
}

// ---------------- bf16 MFMA GEMM, K-step 64 ----------------
// mode 0: fp32 out; 1: bf16 out; 2: fp32 out + fp32 residual;
// mode 3: +res, B = bf16 gate [b][510][n] transposed+padded on the fly (Cs must be 512);
// mode 4: +res, B = attention partials `part` (2-chunk merge + linv normalize on the fly).
__global__ __launch_bounds__(256) void gemm_kernel(const __bf16* __restrict__ A, const __bf16* __restrict__ Bt,
                                                   const float* __restrict__ bias, const float* __restrict__ res,
                                                   float* __restrict__ outf, __bf16* __restrict__ outb,
                                                   const float* __restrict__ part,
                                                   int O, int Cs, int mode) {
  __shared__ __align__(16) __bf16 Asub[64 * 72];
  __shared__ __align__(16) __bf16 Bsub[128 * 72];
  __shared__ float linvS[4][128];
  const int t = threadIdx.x;
  const int lane = t & 63, wv = t >> 6;
  const int q4 = lane >> 4, l16 = lane & 15;
  int o0 = blockIdx.y * 64;
  if (o0 + 64 > O) o0 = O - 64;
  const int ntot0 = blockIdx.x * 128;
  const int b = ntot0 >> 12;
  const int n_in_b0 = ntot0 & 4095;

  if (mode == 4) {
    // per-(head, n) 1/l for this block's 128 n rows
#pragma unroll
    for (int jj = 0; jj < 2; ++jj) {
      int id = t + 256 * jj;
      int h = id >> 7, nl = id & 127;
      int n_in_b = n_in_b0 + nl;
      int ntb = n_in_b >> 6, n64 = n_in_b & 63;
      size_t pb = ((size_t)((b * 4 + h) * 64 + ntb)) * 3136 + 3072 + n64;
      float s = part[pb] + part[pb + (size_t)512 * 3136];
      linvS[h][nl] = rcp_fast(s);
    }
  }

  f32x4 acc[8];
#pragma unroll
  for (int nt = 0; nt < 8; ++nt) acc[nt] = (f32x4){0.f, 0.f, 0.f, 0.f};

  for (int c0 = 0; c0 < Cs; c0 += 64) {
    __syncthreads();
#pragma unroll
    for (int j = 0; j < 2; ++j) {           // A: 64 rows x 64 c
      int id = t + 256 * j;
      *(bf16x8*)&Asub[(id >> 3) * 72 + (id & 7) * 8] =
          *(const bf16x8*)&A[((size_t)(o0 + (id >> 3))) * Cs + c0 + (id & 7) * 8];
    }
    if (mode == 4) {
      // B from attention partials: B[n][c] = (part_ch0 + part_ch1) * linv, c = h*48+cc
#pragma unroll
      for (int j = 0; j < 4; ++j) {
        int id = t + 256 * j;
        int row = id >> 3, cgrp = id & 7;
        int cglob = c0 + cgrp * 8;
        int h = cglob / 48;
        int cc = cglob - h * 48;
        int n_in_b = n_in_b0 + row;
        int ntb = n_in_b >> 6, n64 = n_in_b & 63;
        size_t pb = ((size_t)((b * 4 + h) * 64 + ntb)) * 3136 + (size_t)n64 * 48 + cc;
        f32x4 a0 = *(const f32x4*)&part[pb];
        f32x4 a1 = *(const f32x4*)&part[pb + 4];
        f32x4 b0 = *(const f32x4*)&part[pb + (size_t)512 * 3136];
        f32x4 b1 = *(const f32x4*)&part[pb + (size_t)512 * 3136 + 4];
        float li = linvS[h][row];
        f32x4 s0 = (a0 + b0) * li;
        f32x4 s1 = (a1 + b1) * li;
        bf16x8 ov = { (__bf16)s0.x, (__bf16)s0.y, (__bf16)s0.z, (__bf16)s0.w,
                      (__bf16)s1.x, (__bf16)s1.y, (__bf16)s1.z, (__bf16)s1.w };
        *(bf16x8*)&Bsub[row * 72 + cgrp * 8] = ov;
      }
    } else if (mode != 3) {
#pragma unroll
      for (int j = 0; j < 4; ++j) {         // B: 128 rows x 64 c from [n][c] layout
        int id = t + 256 * j;
        *(bf16x8*)&Bsub[(id >> 3) * 72 + (id & 7) * 8] =
            *(const bf16x8*)&Bt[((size_t)(ntot0 + (id >> 3))) * Cs + c0 + (id & 7) * 8];
      }
    } else {
      // transposing stage from gate [b][510][n]: thread t covers c-row (t&63), 32-n segment (t>>6)
      int cr = t & 63, seg = t >> 6;
      int cg = c0 + cr;
      __bf16 tmp[32];
      if (cg < HIDC) {
        const __bf16* gp = Bt + ((size_t)(b * HIDC + cg)) * HW + n_in_b0 + seg * 32;
#pragma unroll
        for (int j = 0; j < 4; ++j) *(bf16x8*)&tmp[8 * j] = *(const bf16x8*)&gp[8 * j];
      } else {
#pragma unroll
        for (int k = 0; k < 32; ++k) tmp[k] = (__bf16)0.f;
      }
#pragma unroll
      for (int k = 0; k < 32; ++k) Bsub[(seg * 32 + k) * 72 + cr] = tmp[k];
    }
    __syncthreads();
#pragma unroll
    for (int ks = 0; ks < 2; ++ks) {
      bf16x8 af = *(const bf16x8*)&Asub[(16 * wv + l16) * 72 + 32 * ks + 8 * q4];
#pragma unroll
      for (int nt = 0; nt < 8; ++nt) {
        bf16x8 bfr = *(const bf16x8*)&Bsub[(16 * nt + l16) * 72 + 32 * ks + 8 * q4];
        acc[nt] = __builtin_amdgcn_mfma_f32_16x16x32_bf16(af, bfr, acc[nt], 0, 0, 0);
      }
    }
  }

  float bvals[4];
#pragma unroll
  for (int r = 0; r < 4; ++r) bvals[r] = bias[o0 + 16 * wv + 4 * q4 + r];
#pragma unroll
  for (int nt = 0; nt < 8; ++nt) {
    int n_in_b = n_in_b0 + 16 * nt + l16;
#pragma unroll
    for (int r = 0; r < 4; ++r) {
      int o = o0 + 16 * wv + 4 * q4 + r;
      size_t addr = ((size_t)(b * O + o)) * HW + n_in_b;
      float v = acc[nt][r] + bvals[r];
      if (mode >= 2) { outf[addr] = v + res[addr]; }
      else if (mode == 0) { outf[addr] = v; }
      else { outb[addr] = (__bf16)v; }
    }
  }
}

// ---------------- depthwise 3x3 on bf16 qkv; q,k -> qdwb bf16; v -> Vbf bf16 [bh][c][n] ----------------
__global__ __launch_bounds__(256) void dwconv_split_kernel(const __bf16* __restrict__ in, const float* __restrict__ w,
                                                           const float* __restrict__ bias,
                                                           __bf16* __restrict__ qdwb, __bf16* __restrict__ Vbf) {
  int bc = blockIdx.x;
  int b = bc / 576, ch = bc - b * 576;
  __shared__ float tile[66 * 68];
  for (int i = threadIdx.x; i < 66 * 68; i += 256) tile[i] = 0.f;
  __syncthreads();
  const __bf16* p = in + (size_t)bc * HW;
  for (int j = 0; j < 8; ++j) {
    int i = 2 * threadIdx.x + 512 * j;
    bf16x2 v = *(const bf16x2*)&p[i];
    int y = i >> 6, xx = i & 63;
    tile[(y + 1) * 68 + xx + 1] = (float)v.x;
    tile[(y + 1) * 68 + xx + 2] = (float)v.y;
  }
  __syncthreads();
  float w0 = w[ch * 9 + 0], w1 = w[ch * 9 + 1], w2 = w[ch * 9 + 2];
  float w3 = w[ch * 9 + 3], w4 = w[ch * 9 + 4], w5 = w[ch * 9 + 5];
  float w6 = w[ch * 9 + 6], w7 = w[ch * 9 + 7], w8 = w[ch * 9 + 8];
  float bb = bias[ch];
  __bf16* dst;
  if (ch < 384) dst = qdwb + ((size_t)(b * 384 + ch)) * HW;
  else {
    int c = ch - 384, h = c / DH, cc = c - h * DH;
    dst = Vbf + ((size_t)((b * 4 + h) * DH + cc)) * HW;
  }
  for (int j = 0; j < 8; ++j) {
    int i = 2 * threadIdx.x + 512 * j;
    int y = i >> 6, xx = i & 63;
    const float* tt = &tile[y * 68 + xx];
    float a = bb;
    a = fmaf(w0, tt[0], a);   a = fmaf(w1, tt[1], a);   a = fmaf(w2, tt[2], a);
    a = fmaf(w3, tt[68], a);  a = fmaf(w4, tt[69], a);  a = fmaf(w5, tt[70], a);
    a = fmaf(w6, tt[136], a); a = fmaf(w7, tt[137], a); a = fmaf(w8, tt[138], a);
    float a2 = bb;
    a2 = fmaf(w0, tt[1], a2);   a2 = fmaf(w1, tt[2], a2);   a2 = fmaf(w2, tt[3], a2);
    a2 = fmaf(w3, tt[69], a2);  a2 = fmaf(w4, tt[70], a2);  a2 = fmaf(w5, tt[71], a2);
    a2 = fmaf(w6, tt[137], a2); a2 = fmaf(w7, tt[138], a2); a2 = fmaf(w8, tt[139], a2);
    bf16x2 o = { (__bf16)a, (__bf16)a2 };
    *(bf16x2*)&dst[i] = o;
  }
}

// ---------------- GDFN v2: strip compute (1x16 px/thread, b128 LDS reads) + fast gelu ----------------
__global__ __launch_bounds__(256) void gdfn_dw_gate_kernel(const __bf16* __restrict__ hid, const float* __restrict__ w,
                                                           const float* __restrict__ bias, __bf16* __restrict__ gate) {
  int blk = blockIdx.x;           // b*HIDC + j
  int b = blk / HIDC, j = blk - b * HIDC;
  __shared__ __align__(16) float t1[66 * 68];
  __shared__ __align__(16) float t2[66 * 68];
  const int tid = threadIdx.x;
  // halo-only zero init: rows 0 and 65 (all 68 cols), cols {0,65,66,67} for rows 1..64
  if (tid < 136) {
    int r = (tid >= 68) ? 65 : 0;
    int c = (tid >= 68) ? tid - 68 : tid;
    t1[r * 68 + c] = 0.f;
    t2[r * 68 + c] = 0.f;
  }
  {
    int r = (tid >> 2) + 1;
    int c4 = tid & 3;
    int c = (c4 == 0) ? 0 : 64 + c4;   // 0,65,66,67
    t1[r * 68 + c] = 0.f;
    t2[r * 68 + c] = 0.f;
  }
  const __bf16* p1 = hid + ((size_t)b * (2 * HIDC) + j) * HW;
  const __bf16* p2 = p1 + (size_t)HIDC * HW;
  for (int jj = 0; jj < 8; ++jj) {
    int i = 2 * tid + 512 * jj;
    bf16x2 v1 = *(const bf16x2*)&p1[i];
    bf16x2 v2 = *(const bf16x2*)&p2[i];
    int y = i >> 6, xx = i & 63;
    t1[(y + 1) * 68 + xx + 1] = (float)v1.x;
    t1[(y + 1) * 68 + xx + 2] = (float)v1.y;
    t2[(y + 1) * 68 + xx + 1] = (float)v2.x;
    t2[(y + 1) * 68 + xx + 2] = (float)v2.y;
  }
  __syncthreads();
  int c1 = j, c2 = j + HIDC;
  float wa[9], wb[9];
#pragma unroll
  for (int k = 0; k < 9; ++k) { wa[k] = w[c1 * 9 + k]; wb[k] = w[c2 * 9 + k]; }
  float bi1 = bias[c1], bi2 = bias[c2];

  const int y = tid >> 2, x0 = 16 * (tid & 3);
  float x1v[16], x2v[16];
#pragma unroll
  for (int p = 0; p < 16; ++p) { x1v[p] = bi1; x2v[p] = bi2; }
#pragma unroll
  for (int r = 0; r < 3; ++r) {
    const float* rp1 = &t1[(y + r) * 68 + x0];
    float rr[20];
#pragma unroll
    for (int q = 0; q < 5; ++q) *(f32x4*)&rr[4 * q] = *(const f32x4*)&rp1[4 * q];
    float w0 = wa[3 * r], w1 = wa[3 * r + 1], w2 = wa[3 * r + 2];
#pragma unroll
    for (int p = 0; p < 16; ++p)
      x1v[p] = fmaf(w0, rr[p], fmaf(w1, rr[p + 1], fmaf(w2, rr[p + 2], x1v[p])));
  }
#pragma unroll
  for (int r = 0; r < 3; ++r) {
    const float* rp2 = &t2[(y + r) * 68 + x0];
    float rr[20];
#pragma unroll
    for (int q = 0; q < 5; ++q) *(f32x4*)&rr[4 * q] = *(const f32x4*)&rp2[4 * q];
    float w0 = wb[3 * r], w1 = wb[3 * r + 1], w2 = wb[3 * r + 2];
#pragma unroll
    for (int p = 0; p < 16; ++p)
      x2v[p] = fmaf(w0, rr[p], fmaf(w1, rr[p + 1], fmaf(w2, rr[p + 2], x2v[p])));
  }
  __bf16 ob[16];
#pragma unroll
  for (int p = 0; p < 16; ++p) ob[p] = (__bf16)(gelu_fast(x1v[p]) * x2v[p]);
  __bf16* op = gate + ((size_t)b * HIDC + j) * HW + y * 64 + x0;
  *(bf16x8*)&op[0] = *(bf16x8*)&ob[0];
  *(bf16x8*)&op[8] = *(bf16x8*)&ob[8];
}

// ---------------- prep (2-wide, q/k split over blockIdx.y): normalize; fold temp*log2e into q ----------------
__global__ __launch_bounds__(256) void prep_qk_kernel(const __bf16* __restrict__ qdwb, const float* __restrict__ temp,
                                                      __bf16* __restrict__ Qbf, __bf16* __restrict__ Kbf) {
  int t2 = blockIdx.x * 256 + threadIdx.x;   // 0..16383
  int bh = t2 >> 11;
  int np = (t2 & 2047) * 2;
  int b = bh >> 2, h = bh & 3;
  const int isK = blockIdx.y;
  const __bf16* sp = qdwb + ((size_t)(b * 384 + isK * 192 + h * DH)) * HW + np;
  float tq = isK ? 1.f : temp[h] * LOG2E;

  bf16x2 raw[DH];
  float ss0 = 0.f, ss1 = 0.f;
#pragma unroll
  for (int c = 0; c < DH; ++c) {
    bf16x2 v = *(const bf16x2*)&sp[(size_t)c * HW];
    raw[c] = v;
    float f0 = (float)v.x, f1 = (float)v.y;
    ss0 = fmaf(f0, f0, ss0);
    ss1 = fmaf(f1, f1, ss1);
  }
  float sc0 = tq / fmaxf(sqrtf(ss0), 1e-12f);
  float sc1 = tq / fmaxf(sqrtf(ss1), 1e-12f);
  __bf16 ob0[64], ob1[64];
#pragma unroll
  for (int c = 0; c < DH; ++c) {
    ob0[c] = (__bf16)((float)raw[c].x * sc0);
    ob1[c] = (__bf16)((float)raw[c].y * sc1);
  }
#pragma unroll
  for (int c = DH; c < 64; ++c) { ob0[c] = (__bf16)0.f; ob1[c] = (__bf16)0.f; }
  __bf16* dd = (isK ? Kbf : Qbf) + ((size_t)(bh << 12) + np) * 64;
#pragma unroll
  for (int ch = 0; ch < 8; ++ch) {
    *(bf16x8*)&dd[ch * 8] = *(bf16x8*)&ob0[ch * 8];
    *(bf16x8*)&dd[64 + ch * 8] = *(bf16x8*)&ob1[ch * 8];
  }
}

// ---------------- flash attention split-K v10: K-direct regs + dbuf LDS, 1 barrier/iter, ptr-bump ----------------
// grid 1024 = chunk*512 + bh*64 + nt; block 256 (4 waves).
__global__ __launch_bounds__(256) void attn_split_kernel(const __bf16* __restrict__ Qbf, const __bf16* __restrict__ Kbf,
                                                         const __bf16* __restrict__ Vbf, float* __restrict__ part) {
  __shared__ __align__(16) __bf16 Vc[2][48 * 72];   // Vc[buf][c][m]
  __shared__ __align__(16) __bf16 Pl[2][64 * 72];   // Pl[buf][n][m] (Pl[0] reused as Lred in epilogue)
  const int tid = threadIdx.x;
  const int lane = tid & 63;
  const int wv = tid >> 6;
  const int q4 = lane >> 4, l16 = lane & 15;
  const int bid = blockIdx.x;
  const int chunk = bid >> 9, rest = bid & 511;
  const int bh = rest >> 6, nt = rest & 63;
  const int n0 = nt * 64;
  const __bf16* Qg = Qbf + (size_t)bh * HW * 64;
  const __bf16* Kg = Kbf + (size_t)bh * HW * 64;
  const __bf16* Vg = Vbf + (size_t)bh * DH * HW;

  // Q fragments in registers (B-operand of S^T): qf[s][ks] = Q[n0+16s+l16][32ks+8q4 ..+7]
  bf16x8 qf[4][2];
#pragma unroll
  for (int s = 0; s < 4; ++s)
#pragma unroll
    for (int ks = 0; ks < 2; ++ks)
      qf[s][ks] = *(const bf16x8*)&Qg[((size_t)(n0 + 16 * s + l16)) * 64 + 32 * ks + 8 * q4];

  // K fragment pointers (per-wave rows) and V staging pointers; bump by one m-tile per iter.
  const int m0 = chunk * 2048;   // 32 m-tiles * 64
  const __bf16* kp0 = Kg + ((size_t)(m0 + 16 * wv + l16)) * 64 + 8 * q4;
  const __bf16* kp1 = kp0 + 32;
  const __bf16* vp0 = Vg + ((size_t)(tid >> 3)) * HW + m0 + (tid & 7) * 8;
  const __bf16* vp1 = Vg + ((size_t)((tid + 256) >> 3)) * HW + m0 + ((tid + 256) & 7) * 8;
  bf16x8 kf0 = *(const bf16x8*)kp0;
  bf16x8 kf1 = *(const bf16x8*)kp1;
  bf16x8 vreg[2];
  vreg[0] = *(const bf16x8*)vp0;
  if (tid < 128) vreg[1] = *(const bf16x8*)vp1;

  float lsub[4] = {0.f, 0.f, 0.f, 0.f};
  f32x4 oacc[3];
#pragma unroll
  for (int ct = 0; ct < 3; ++ct) oacc[ct] = (f32x4){0.f, 0.f, 0.f, 0.f};

  for (int it = 0; it < 32; ++it) {
    const int cur = it & 1;
    // write prefetched V regs -> LDS buffer `cur` (prior PV readers used buffer cur^1)
    *(bf16x8*)&Vc[cur][(tid >> 3) * 72 + (tid & 7) * 8] = vreg[0];
    if (tid < 128) {
      int i = tid + 256;
      *(bf16x8*)&Vc[cur][(i >> 3) * 72 + (i & 7) * 8] = vreg[1];
    }
    // issue next iteration's global loads (pointer bumps; final-iter over-read stays in workspace, unused)
    kp0 += 4096; kp1 += 4096; vp0 += 64; vp1 += 64;
    bf16x8 kn0 = *(const bf16x8*)kp0;
    bf16x8 kn1 = *(const bf16x8*)kp1;
    vreg[0] = *(const bf16x8*)vp0;
    if (tid < 128) vreg[1] = *(const bf16x8*)vp1;

    // S^T[m][n] = K·Q^T: pure-register MFMA
    f32x4 sacc[4];
#pragma unroll
    for (int s = 0; s < 4; ++s) sacc[s] = (f32x4){0.f, 0.f, 0.f, 0.f};
    __builtin_amdgcn_s_setprio(1);
#pragma unroll
    for (int s = 0; s < 4; ++s)
      sacc[s] = __builtin_amdgcn_mfma_f32_16x16x32_bf16(kf0, qf[s][0], sacc[s], 0, 0, 0);
#pragma unroll
    for (int s = 0; s < 4; ++s)
      sacc[s] = __builtin_amdgcn_mfma_f32_16x16x32_bf16(kf1, qf[s][1], sacc[s], 0, 0, 0);
    __builtin_amdgcn_s_setprio(0);

    // maxless softmax (log2e pre-folded into Q); raw v_exp; packed b64 P writes (m-contig)
#pragma unroll
    for (int s = 0; s < 4; ++s) {
      float p0 = exp2_fast(sacc[s][0]);
      float p1 = exp2_fast(sacc[s][1]);
      float p2 = exp2_fast(sacc[s][2]);
      float p3 = exp2_fast(sacc[s][3]);
      lsub[s] += (p0 + p1) + (p2 + p3);
      bf16x4 pk = { (__bf16)p0, (__bf16)p1, (__bf16)p2, (__bf16)p3 };
      *(bf16x4*)&Pl[cur][(16 * s + l16) * 72 + 16 * wv + 4 * q4] = pk;
    }
    __syncthreads();                     // publish Vc[cur] + Pl[cur] (the ONLY barrier per iter)

    // O[n][c] += P·V^T: wave owns n-strip 16wv
    __builtin_amdgcn_s_setprio(1);
#pragma unroll
    for (int ks = 0; ks < 2; ++ks) {
      bf16x8 pf = *(const bf16x8*)&Pl[cur][(16 * wv + l16) * 72 + 32 * ks + 8 * q4];
#pragma unroll
      for (int ct = 0; ct < 3; ++ct) {
        bf16x8 vf = *(const bf16x8*)&Vc[cur][(16 * ct + l16) * 72 + 32 * ks + 8 * q4];
        oacc[ct] = __builtin_amdgcn_mfma_f32_16x16x32_bf16(pf, vf, oacc[ct], 0, 0, 0);
      }
    }
    __builtin_amdgcn_s_setprio(0);
    kf0 = kn0; kf1 = kn1;
  }

  // epilogue
  __syncthreads();
  float* Lred = (float*)&Pl[0][0];
#pragma unroll
  for (int s = 0; s < 4; ++s) {
    float v = lsub[s];
    v += __shfl_xor(v, 16, 64);
    v += __shfl_xor(v, 32, 64);
    if (q4 == 0) Lred[wv * 64 + 16 * s + l16] = v;
  }
  __syncthreads();
  size_t pbase = (size_t)bid * 3136;
  if (tid < 64)
    part[pbase + 3072 + tid] = Lred[tid] + Lred[64 + tid] + Lred[128 + tid] + Lred[192 + tid];
#pragma unroll
  for (int ct = 0; ct < 3; ++ct)
#pragma unroll
    for (int r = 0; r < 4; ++r) {
      int n = 16 * wv + 4 * q4 + r;
      part[pbase + (size_t)n * 48 + 16 * ct + l16] = oacc[ct][r];
    }
}

extern "C" void kernel_launch(void* const* d_in, const int* in_sizes, int n_in,
                              void* d_out, int out_size, void* d_ws, size_t ws_size,
                              hipStream_t stream) {
  const float* x        = (const float*)d_in[0];
  const float* ln1_w    = (const float*)d_in[1];
  const float* ln1_b    = (const float*)d_in[2];
  const float* qkv_w    = (const float*)d_in[3];
  const float* qkv_b    = (const float*)d_in[4];
  const float* qkv_dw_w = (const float*)d_in[5];
  const float* qkv_dw_b = (const float*)d_in[6];
  const float* temperature = (const float*)d_in[7];
  const float* proj_w   = (const float*)d_in[8];
  const float* proj_b   = (const float*)d_in[9];
  const float* ln2_w    = (const float*)d_in[10];
  const float* ln2_b    = (const float*)d_in[11];
  const float* pin_w    = (const float*)d_in[12];
  const float* pin_b    = (const float*)d_in[13];
  const float* gdfn_dw_w = (const float*)d_in[14];
  const float* gdfn_dw_b = (const float*)d_in[15];
  const float* pout_w   = (const float*)d_in[16];
  const float* pout_b   = (const float*)d_in[17];
  float* out = (float*)d_out;
  float* ws = (float*)d_ws;

  // ---- workspace layout (float offsets) ----
  __bf16* wb_qkv  = (__bf16*)(ws + 0);          // 55296 f
  __bf16* wb_proj = (__bf16*)(ws + 55296);      // 18432 f
  __bf16* wb_pin  = (__bf16*)(ws + 73728);      // 97920 f
  __bf16* wb_pout = (__bf16*)(ws + 171648);     // 49152 f
  float* sc1 = ws + 220800;
  float* sh1 = ws + 221184;
  float* sc2 = ws + 221568;
  float* sh2 = ws + 221952;                     // ends 222336
  // region B @222336: Xt1/Xt2 overlap Qbf; Q/K/V bf16
  __bf16* Xt1 = (__bf16*)(ws + 222336);
  __bf16* Xt2 = (__bf16*)(ws + 222336);
  __bf16* Qbf = (__bf16*)(ws + 222336);         // 1,048,576 f
  __bf16* Kbf = (__bf16*)(ws + 1270912);        // 1,048,576 f
  __bf16* Vbf = (__bf16*)(ws + 2319488);        // 786,432 f -> ends 3,105,920
  // region C @3,105,920: qkvb bf16 -> later hid
  __bf16* qkvb   = (__bf16*)(ws + 3105920);
  __bf16* hid    = (__bf16*)(ws + 3105920);     // ends 7,283,840
  // region D @5,465,216: qdwb (dead before attn) then Opart (1024 blocks)
  __bf16* qdwb  = (__bf16*)(ws + 5465216);
  float*  Opart = ws + 5465216;                 // 1024*3136 = 3,211,264 f -> ends 8,676,480
  __bf16* gate  = (__bf16*)(ws + 7283840);      // 2,088,960 f (phase B, Opart dead)
  // total 11,887,744 f = 47.6 MB

  // ---- phase A ----
  wcvt_ln_kernel<<<1725 + 2 * DIMC, 256, 0, stream>>>(qkv_w, proj_w, pin_w, pout_w,
                                                      wb_qkv, wb_proj, wb_pin, wb_pout,
                                                      x, ln1_w, ln1_b, sc1, sh1);
  ln_apply_t_kernel<<<dim3(64, 6, 2), 256, 0, stream>>>(x, sc1, sh1, Xt1);
  gemm_kernel<<<dim3(64, 9), 256, 0, stream>>>(wb_qkv, Xt1, qkv_b, nullptr, nullptr, qkvb, nullptr, 576, 192, 1);
  dwconv_split_kernel<<<1152, 256, 0, stream>>>(qkvb, qkv_dw_w, qkv_dw_b, qdwb, Vbf);
  prep_qk_kernel<<<dim3(64, 2), 256, 0, stream>>>(qdwb, temperature, Qbf, Kbf);
  attn_split_kernel<<<1024, 256, 0, stream>>>(Qbf, Kbf, Vbf, Opart);
  gemm_kernel<<<dim3(64, 3), 256, 0, stream>>>(wb_proj, nullptr, proj_b, x, out, nullptr, Opart, 192, 192, 4);

  // ---- phase B ----
  ln_stats_kernel<<<2 * DIMC, 256, 0, stream>>>(out, ln2_w, ln2_b, sc2, sh2);
  ln_apply_t_kernel<<<dim3(64, 6, 2), 256, 0, stream>>>(out, sc2, sh2, Xt2);
  gemm_kernel<<<dim3(64, 16), 256, 0, stream>>>(wb_pin, Xt2, pin_b, nullptr, nullptr, hid, nullptr, 1020, 192, 1);
  gdfn_dw_gate_kernel<<<2 * HIDC, 256, 0, stream>>>(hid, gdfn_dw_w, gdfn_dw_b, gate);
  gemm_kernel<<<dim3(64, 3), 256, 0, stream>>>(wb_pout, (const __bf16*)gate, pout_b, out, out, nullptr, nullptr, 192, 512, 3);
}

// Round 11
// 233.787 us; speedup vs baseline: 1.0968x; 1.0217x over previous
//
#include <hip/hip_runtime.h>
#include <hip/hip_bf16.h>

typedef __bf16 bf16x8 __attribute__((ext_vector_type(8)));
typedef __bf16 bf16x4 __attribute__((ext_vector_type(4)));
typedef __bf16 bf16x2 __attribute__((ext_vector_type(2)));
typedef float f32x4 __attribute__((ext_vector_type(4)));

#define HW 4096
#define DIMC 192
#define DH 48
#define HIDC 510
#define LOG2E 1.44269504088896f

// raw v_exp_f32 (2^x): skip the ocml range/denorm fixups (r5: -19us in attn).
__device__ __forceinline__ float exp2_fast(float x) {
#if __has_builtin(__builtin_amdgcn_exp2f)
  return __builtin_amdgcn_exp2f(x);
#else
  float r;
  asm("v_exp_f32 %0, %1\n\ts_nop 1" : "=v"(r) : "v"(x));
  return r;
#endif
}

__device__ __forceinline__ float rcp_fast(float x) {
#if __has_builtin(__builtin_amdgcn_rcpf)
  return __builtin_amdgcn_rcpf(x);
#else
  float r;
  asm("v_rcp_f32 %0, %1\n\ts_nop 1" : "=v"(r) : "v"(x));
  return r;
#endif
}

// gelu via A&S 7.1.26 erf (|err|<=1.5e-7) on exp2_fast+rcp_fast — no ocml call.
__device__ __forceinline__ float gelu_fast(float x) {
  float z = fabsf(x) * 0.70710678118654752f;
  float t = rcp_fast(fmaf(0.3275911f, z, 1.f));
  float p = t * fmaf(t, fmaf(t, fmaf(t, fmaf(t, 1.061405429f, -1.453152027f), 1.421413741f), -0.284496736f), 0.254829592f);
  float e = exp2_fast(-z * z * 1.4426950408889634f);
  float erfa = 1.f - p * e;          // erf(|x|/sqrt2)
  float erfx = copysignf(erfa, x);
  return 0.5f * x * (1.f + erfx);
}

// ---------------- combo: weight convert (blocks 0..1724) + LN1 stats (blocks 1725..2108) ----------------
// block 0 also zeroes the phase-B LN accumulator (lnsum[768], consumed by proj-gemm atomics much later).
__global__ __launch_bounds__(256) void wcvt_ln_kernel(const float* __restrict__ qkv_w, const float* __restrict__ proj_w,
                                                      const float* __restrict__ pin_w, const float* __restrict__ pout_w,
                                                      __bf16* __restrict__ wb_qkv, __bf16* __restrict__ wb_proj,
                                                      __bf16* __restrict__ wb_pin, __bf16* __restrict__ wb_pout,
                                                      const float* __restrict__ x, const float* __restrict__ lw,
                                                      const float* __restrict__ lb, float* __restrict__ sc,
                                                      float* __restrict__ sh, float* __restrict__ lnsum) {
  __shared__ float red[8];
  if (blockIdx.x < 1725) {
    if (blockIdx.x == 0) {
      for (int i = threadIdx.x; i < 768; i += 256) lnsum[i] = 0.f;
    }
    int idx = blockIdx.x * 256 + threadIdx.x;
    if (idx < 110592) {                       // qkv 576x192
      wb_qkv[idx] = (__bf16)qkv_w[idx];
    } else if (idx < 147456) {                // proj 192x192
      int i = idx - 110592;
      wb_proj[i] = (__bf16)proj_w[i];
    } else if (idx < 343296) {                // pin 1020x192
      int i = idx - 147456;
      wb_pin[i] = (__bf16)pin_w[i];
    } else if (idx < 441600) {                // pout 192x512 (pad c 510,511)
      int i = idx - 343296;
      int o = i >> 9, c = i & 511;
      wb_pout[i] = (c < HIDC) ? (__bf16)pout_w[o * HIDC + c] : (__bf16)0.f;
    }
    return;
  }
  int bc = blockIdx.x - 1725;     // b*DIMC + c
  int c = bc % DIMC;
  const float* row = x + (size_t)bc * HW;
  float s = 0.f, s2 = 0.f;
  for (int i = threadIdx.x * 4; i < HW; i += 1024) {
    f32x4 v = *(const f32x4*)&row[i];
    s += (v.x + v.y) + (v.z + v.w);
    s2 = fmaf(v.x, v.x, s2); s2 = fmaf(v.y, v.y, s2);
    s2 = fmaf(v.z, v.z, s2); s2 = fmaf(v.w, v.w, s2);
  }
  for (int off = 32; off; off >>= 1) { s += __shfl_down(s, off, 64); s2 += __shfl_down(s2, off, 64); }
  int wid = threadIdx.x >> 6;
  if ((threadIdx.x & 63) == 0) { red[wid] = s; red[4 + wid] = s2; }
  __syncthreads();
  if (threadIdx.x == 0) {
    s = red[0] + red[1] + red[2] + red[3];
    s2 = red[4] + red[5] + red[6] + red[7];
    float mean = s * (1.f / HW);
    float var = s2 * (1.f / HW) - mean * mean;
    float rstd = rsqrtf(var + 1e-6f);
    float scv = rstd * lw[c];
    sc[bc] = scv;
    sh[bc] = lb[c] - mean * scv;
  }
}

// ---------------- LN apply + transpose-convert: fp32 [b][192][n] -> bf16 Xt[(b*4096+n)][192] ----------------
__global__ __launch_bounds__(256) void ln_apply_t_kernel(const float* __restrict__ x, const float* __restrict__ sc,
                                                         const float* __restrict__ sh, __bf16* __restrict__ Xt) {
  int n0 = blockIdx.x * 64, c0 = blockIdx.y * 32, b = blockIdx.z;
  int t = threadIdx.x;
  int n = t & 63, cs = c0 + (t >> 6) * 8;
  __bf16 ob[8];
#pragma unroll
  for (int cc = 0; cc < 8; ++cc) {
    int c = cs + cc;
    float v = fmaf(x[((size_t)(b * DIMC + c)) * HW + n0 + n], sc[b * DIMC + c], sh[b * DIMC + c]);
    ob[cc] = (__bf16)v;
  }
  *(bf16x8*)&Xt[((size_t)((b << 12) + n0 + n)) * DIMC + cs] = *(bf16x8*)ob;
}

// ---------------- LN apply from raw sums (phase B): sc/sh computed inline from lnsum ----------------
__global__ __launch_bounds__(256) void ln_apply_t_sum_kernel(const float* __restrict__ x, const float* __restrict__ lnsum,
                                                             const float* __restrict__ w, const float* __restrict__ bb,
                                                             __bf16* __restrict__ Xt) {
  int n0 = blockIdx.x * 64, c0 = blockIdx.y * 32, b = blockIdx.z;
  int t = threadIdx.x;
  int n = t & 63, cs = c0 + (t >> 6) * 8;
  __bf16 ob[8];
#pragma unroll
  for (int cc = 0; cc < 8; ++cc) {
    int c = cs + cc;
    float mean = lnsum[b * DIMC + c] * (1.f / HW);
    float var = lnsum[384 + b * DIMC + c] * (1.f / HW) - mean * mean;
    float rstd = rsqrtf(var + 1e-6f);
    float scv = rstd * w[c];
    float shv = bb[c] - mean * scv;
    float v = fmaf(x[((size_t)(b * DIMC + c)) * HW + n0 + n], scv, shv);
    ob[cc] = (__bf16)v;
  }
  *(bf16x8*)&Xt[((size_t)((b << 12) + n0 + n)) * DIMC + cs] = *(bf16x8*)ob;
}

// ---------------- bf16 MFMA GEMM, K-step 64 ----------------
// mode 0: fp32 out; 1: bf16 out; 2: fp32 out + fp32 residual;
// mode 3: +res, B = bf16 gate [b][510][n] transposed+padded on the fly (Cs must be 512);
// mode 4: +res, B = attention partials `part` (2-chunk merge + linv normalize on the fly),
//         and epilogue accumulates per-(b,o) sum/sumsq of the output into lnsum (LN2 stats fusion).
__global__ __launch_bounds__(256) void gemm_kernel(const __bf16* __restrict__ A, const __bf16* __restrict__ Bt,
                                                   const float* __restrict__ bias, const float* __restrict__ res,
                                                   float* __restrict__ outf, __bf16* __restrict__ outb,
                                                   const float* __restrict__ part, float* __restrict__ lnsum,
                                                   int O, int Cs, int mode) {
  __shared__ __align__(16) __bf16 Asub[64 * 72];
  __shared__ __align__(16) __bf16 Bsub[128 * 72];
  __shared__ float linvS[4][128];
  const int t = threadIdx.x;
  const int lane = t & 63, wv = t >> 6;
  const int q4 = lane >> 4, l16 = lane & 15;
  int o0 = blockIdx.y * 64;
  if (o0 + 64 > O) o0 = O - 64;
  const int ntot0 = blockIdx.x * 128;
  const int b = ntot0 >> 12;
  const int n_in_b0 = ntot0 & 4095;

  if (mode == 4) {
    // per-(head, n) 1/l for this block's 128 n rows
#pragma unroll
    for (int jj = 0; jj < 2; ++jj) {
      int id = t + 256 * jj;
      int h = id >> 7, nl = id & 127;
      int n_in_b = n_in_b0 + nl;
      int ntb = n_in_b >> 6, n64 = n_in_b & 63;
      size_t pb = ((size_t)((b * 4 + h) * 64 + ntb)) * 3136 + 3072 + n64;
      float s = part[pb] + part[pb + (size_t)512 * 3136];
      linvS[h][nl] = rcp_fast(s);
    }
  }

  f32x4 acc[8];
#pragma unroll
  for (int nt = 0; nt < 8; ++nt) acc[nt] = (f32x4){0.f, 0.f, 0.f, 0.f};

  for (int c0 = 0; c0 < Cs; c0 += 64) {
    __syncthreads();
#pragma unroll
    for (int j = 0; j < 2; ++j) {           // A: 64 rows x 64 c
      int id = t + 256 * j;
      *(bf16x8*)&Asub[(id >> 3) * 72 + (id & 7) * 8] =
          *(const bf16x8*)&A[((size_t)(o0 + (id >> 3))) * Cs + c0 + (id & 7) * 8];
    }
    if (mode == 4) {
      // B from attention partials: B[n][c] = (part_ch0 + part_ch1) * linv, c = h*48+cc
#pragma unroll
      for (int j = 0; j < 4; ++j) {
        int id = t + 256 * j;
        int row = id >> 3, cgrp = id & 7;
        int cglob = c0 + cgrp * 8;
        int h = cglob / 48;
        int cc = cglob - h * 48;
        int n_in_b = n_in_b0 + row;
        int ntb = n_in_b >> 6, n64 = n_in_b & 63;
        size_t pb = ((size_t)((b * 4 + h) * 64 + ntb)) * 3136 + (size_t)n64 * 48 + cc;
        f32x4 a0 = *(const f32x4*)&part[pb];
        f32x4 a1 = *(const f32x4*)&part[pb + 4];
        f32x4 b0 = *(const f32x4*)&part[pb + (size_t)512 * 3136];
        f32x4 b1 = *(const f32x4*)&part[pb + (size_t)512 * 3136 + 4];
        float li = linvS[h][row];
        f32x4 s0 = (a0 + b0) * li;
        f32x4 s1 = (a1 + b1) * li;
        bf16x8 ov = { (__bf16)s0.x, (__bf16)s0.y, (__bf16)s0.z, (__bf16)s0.w,
                      (__bf16)s1.x, (__bf16)s1.y, (__bf16)s1.z, (__bf16)s1.w };
        *(bf16x8*)&Bsub[row * 72 + cgrp * 8] = ov;
      }
    } else if (mode != 3) {
#pragma unroll
      for (int j = 0; j < 4; ++j) {         // B: 128 rows x 64 c from [n][c] layout
        int id = t + 256 * j;
        *(bf16x8*)&Bsub[(id >> 3) * 72 + (id & 7) * 8] =
            *(const bf16x8*)&Bt[((size_t)(ntot0 + (id >> 3))) * Cs + c0 + (id & 7) * 8];
      }
    } else {
      // transposing stage from gate [b][510][n]: thread t covers c-row (t&63), 32-n segment (t>>6)
      int cr = t & 63, seg = t >> 6;
      int cg = c0 + cr;
      __bf16 tmp[32];
      if (cg < HIDC) {
        const __bf16* gp = Bt + ((size_t)(b * HIDC + cg)) * HW + n_in_b0 + seg * 32;
#pragma unroll
        for (int j = 0; j < 4; ++j) *(bf16x8*)&tmp[8 * j] = *(const bf16x8*)&gp[8 * j];
      } else {
#pragma unroll
        for (int k = 0; k < 32; ++k) tmp[k] = (__bf16)0.f;
      }
#pragma unroll
      for (int k = 0; k < 32; ++k) Bsub[(seg * 32 + k) * 72 + cr] = tmp[k];
    }
    __syncthreads();
#pragma unroll
    for (int ks = 0; ks < 2; ++ks) {
      bf16x8 af = *(const bf16x8*)&Asub[(16 * wv + l16) * 72 + 32 * ks + 8 * q4];
#pragma unroll
      for (int nt = 0; nt < 8; ++nt) {
        bf16x8 bfr = *(const bf16x8*)&Bsub[(16 * nt + l16) * 72 + 32 * ks + 8 * q4];
        acc[nt] = __builtin_amdgcn_mfma_f32_16x16x32_bf16(af, bfr, acc[nt], 0, 0, 0);
      }
    }
  }

  float bvals[4];
#pragma unroll
  for (int r = 0; r < 4; ++r) bvals[r] = bias[o0 + 16 * wv + 4 * q4 + r];
  float osum[4] = {0.f, 0.f, 0.f, 0.f}, osq[4] = {0.f, 0.f, 0.f, 0.f};
#pragma unroll
  for (int nt = 0; nt < 8; ++nt) {
    int n_in_b = n_in_b0 + 16 * nt + l16;
#pragma unroll
    for (int r = 0; r < 4; ++r) {
      int o = o0 + 16 * wv + 4 * q4 + r;
      size_t addr = ((size_t)(b * O + o)) * HW + n_in_b;
      float v = acc[nt][r] + bvals[r];
      if (mode >= 2) { v += res[addr]; outf[addr] = v; }
      else if (mode == 0) { outf[addr] = v; }
      else { outb[addr] = (__bf16)v; }
      if (mode == 4) { osum[r] += v; osq[r] = fmaf(v, v, osq[r]); }
    }
  }
  if (mode == 4) {
    // lane-reduce over l16 (n-dimension), then one atomic pair per (b,o) per block
#pragma unroll
    for (int r = 0; r < 4; ++r) {
      float s = osum[r], s2 = osq[r];
#pragma unroll
      for (int off = 1; off < 16; off <<= 1) {
        s += __shfl_xor(s, off, 64);
        s2 += __shfl_xor(s2, off, 64);
      }
      if (l16 == 0) {
        int o = o0 + 16 * wv + 4 * q4 + r;
        atomicAdd(&lnsum[b * DIMC + o], s);
        atomicAdd(&lnsum[384 + b * DIMC + o], s2);
      }
    }
  }
}

// ---------------- depthwise 3x3 on bf16 qkv; q,k -> qdwb bf16; v -> Vbf bf16 [bh][c][n] ----------------
__global__ __launch_bounds__(256) void dwconv_split_kernel(const __bf16* __restrict__ in, const float* __restrict__ w,
                                                           const float* __restrict__ bias,
                                                           __bf16* __restrict__ qdwb, __bf16* __restrict__ Vbf) {
  int bc = blockIdx.x;
  int b = bc / 576, ch = bc - b * 576;
  __shared__ float tile[66 * 68];
  for (int i = threadIdx.x; i < 66 * 68; i += 256) tile[i] = 0.f;
  __syncthreads();
  const __bf16* p = in + (size_t)bc * HW;
  for (int j = 0; j < 8; ++j) {
    int i = 2 * threadIdx.x + 512 * j;
    bf16x2 v = *(const bf16x2*)&p[i];
    int y = i >> 6, xx = i & 63;
    tile[(y + 1) * 68 + xx + 1] = (float)v.x;
    tile[(y + 1) * 68 + xx + 2] = (float)v.y;
  }
  __syncthreads();
  float w0 = w[ch * 9 + 0], w1 = w[ch * 9 + 1], w2 = w[ch * 9 + 2];
  float w3 = w[ch * 9 + 3], w4 = w[ch * 9 + 4], w5 = w[ch * 9 + 5];
  float w6 = w[ch * 9 + 6], w7 = w[ch * 9 + 7], w8 = w[ch * 9 + 8];
  float bb = bias[ch];
  __bf16* dst;
  if (ch < 384) dst = qdwb + ((size_t)(b * 384 + ch)) * HW;
  else {
    int c = ch - 384, h = c / DH, cc = c - h * DH;
    dst = Vbf + ((size_t)((b * 4 + h) * DH + cc)) * HW;
  }
  for (int j = 0; j < 8; ++j) {
    int i = 2 * threadIdx.x + 512 * j;
    int y = i >> 6, xx = i & 63;
    const float* tt = &tile[y * 68 + xx];
    float a = bb;
    a = fmaf(w0, tt[0], a);   a = fmaf(w1, tt[1], a);   a = fmaf(w2, tt[2], a);
    a = fmaf(w3, tt[68], a);  a = fmaf(w4, tt[69], a);  a = fmaf(w5, tt[70], a);
    a = fmaf(w6, tt[136], a); a = fmaf(w7, tt[137], a); a = fmaf(w8, tt[138], a);
    float a2 = bb;
    a2 = fmaf(w0, tt[1], a2);   a2 = fmaf(w1, tt[2], a2);   a2 = fmaf(w2, tt[3], a2);
    a2 = fmaf(w3, tt[69], a2);  a2 = fmaf(w4, tt[70], a2);  a2 = fmaf(w5, tt[71], a2);
    a2 = fmaf(w6, tt[137], a2); a2 = fmaf(w7, tt[138], a2); a2 = fmaf(w8, tt[139], a2);
    bf16x2 o = { (__bf16)a, (__bf16)a2 };
    *(bf16x2*)&dst[i] = o;
  }
}

// ---------------- GDFN v2: strip compute (1x16 px/thread, b128 LDS reads) + fast gelu ----------------
__global__ __launch_bounds__(256) void gdfn_dw_gate_kernel(const __bf16* __restrict__ hid, const float* __restrict__ w,
                                                           const float* __restrict__ bias, __bf16* __restrict__ gate) {
  int blk = blockIdx.x;           // b*HIDC + j
  int b = blk / HIDC, j = blk - b * HIDC;
  __shared__ __align__(16) float t1[66 * 68];
  __shared__ __align__(16) float t2[66 * 68];
  const int tid = threadIdx.x;
  // halo-only zero init: rows 0 and 65 (all 68 cols), cols {0,65,66,67} for rows 1..64
  if (tid < 136) {
    int r = (tid >= 68) ? 65 : 0;
    int c = (tid >= 68) ? tid - 68 : tid;
    t1[r * 68 + c] = 0.f;
    t2[r * 68 + c] = 0.f;
  }
  {
    int r = (tid >> 2) + 1;
    int c4 = tid & 3;
    int c = (c4 == 0) ? 0 : 64 + c4;   // 0,65,66,67
    t1[r * 68 + c] = 0.f;
    t2[r * 68 + c] = 0.f;
  }
  const __bf16* p1 = hid + ((size_t)b * (2 * HIDC) + j) * HW;
  const __bf16* p2 = p1 + (size_t)HIDC * HW;
  for (int jj = 0; jj < 8; ++jj) {
    int i = 2 * tid + 512 * jj;
    bf16x2 v1 = *(const bf16x2*)&p1[i];
    bf16x2 v2 = *(const bf16x2*)&p2[i];
    int y = i >> 6, xx = i & 63;
    t1[(y + 1) * 68 + xx + 1] = (float)v1.x;
    t1[(y + 1) * 68 + xx + 2] = (float)v1.y;
    t2[(y + 1) * 68 + xx + 1] = (float)v2.x;
    t2[(y + 1) * 68 + xx + 2] = (float)v2.y;
  }
  __syncthreads();
  int c1 = j, c2 = j + HIDC;
  float wa[9], wb[9];
#pragma unroll
  for (int k = 0; k < 9; ++k) { wa[k] = w[c1 * 9 + k]; wb[k] = w[c2 * 9 + k]; }
  float bi1 = bias[c1], bi2 = bias[c2];

  const int y = tid >> 2, x0 = 16 * (tid & 3);
  float x1v[16], x2v[16];
#pragma unroll
  for (int p = 0; p < 16; ++p) { x1v[p] = bi1; x2v[p] = bi2; }
#pragma unroll
  for (int r = 0; r < 3; ++r) {
    const float* rp1 = &t1[(y + r) * 68 + x0];
    float rr[20];
#pragma unroll
    for (int q = 0; q < 5; ++q) *(f32x4*)&rr[4 * q] = *(const f32x4*)&rp1[4 * q];
    float w0 = wa[3 * r], w1 = wa[3 * r + 1], w2 = wa[3 * r + 2];
#pragma unroll
    for (int p = 0; p < 16; ++p)
      x1v[p] = fmaf(w0, rr[p], fmaf(w1, rr[p + 1], fmaf(w2, rr[p + 2], x1v[p])));
  }
#pragma unroll
  for (int r = 0; r < 3; ++r) {
    const float* rp2 = &t2[(y + r) * 68 + x0];
    float rr[20];
#pragma unroll
    for (int q = 0; q < 5; ++q) *(f32x4*)&rr[4 * q] = *(const f32x4*)&rp2[4 * q];
    float w0 = wb[3 * r], w1 = wb[3 * r + 1], w2 = wb[3 * r + 2];
#pragma unroll
    for (int p = 0; p < 16; ++p)
      x2v[p] = fmaf(w0, rr[p], fmaf(w1, rr[p + 1], fmaf(w2, rr[p + 2], x2v[p])));
  }
  __bf16 ob[16];
#pragma unroll
  for (int p = 0; p < 16; ++p) ob[p] = (__bf16)(gelu_fast(x1v[p]) * x2v[p]);
  __bf16* op = gate + ((size_t)b * HIDC + j) * HW + y * 64 + x0;
  *(bf16x8*)&op[0] = *(bf16x8*)&ob[0];
  *(bf16x8*)&op[8] = *(bf16x8*)&ob[8];
}

// ---------------- prep (2-wide, q/k split over blockIdx.y): normalize; fold temp*log2e into q ----------------
__global__ __launch_bounds__(256) void prep_qk_kernel(const __bf16* __restrict__ qdwb, const float* __restrict__ temp,
                                                      __bf16* __restrict__ Qbf, __bf16* __restrict__ Kbf) {
  int t2 = blockIdx.x * 256 + threadIdx.x;   // 0..16383
  int bh = t2 >> 11;
  int np = (t2 & 2047) * 2;
  int b = bh >> 2, h = bh & 3;
  const int isK = blockIdx.y;
  const __bf16* sp = qdwb + ((size_t)(b * 384 + isK * 192 + h * DH)) * HW + np;
  float tq = isK ? 1.f : temp[h] * LOG2E;

  bf16x2 raw[DH];
  float ss0 = 0.f, ss1 = 0.f;
#pragma unroll
  for (int c = 0; c < DH; ++c) {
    bf16x2 v = *(const bf16x2*)&sp[(size_t)c * HW];
    raw[c] = v;
    float f0 = (float)v.x, f1 = (float)v.y;
    ss0 = fmaf(f0, f0, ss0);
    ss1 = fmaf(f1, f1, ss1);
  }
  float sc0 = tq / fmaxf(sqrtf(ss0), 1e-12f);
  float sc1 = tq / fmaxf(sqrtf(ss1), 1e-12f);
  __bf16 ob0[64], ob1[64];
#pragma unroll
  for (int c = 0; c < DH; ++c) {
    ob0[c] = (__bf16)((float)raw[c].x * sc0);
    ob1[c] = (__bf16)((float)raw[c].y * sc1);
  }
#pragma unroll
  for (int c = DH; c < 64; ++c) { ob0[c] = (__bf16)0.f; ob1[c] = (__bf16)0.f; }
  __bf16* dd = (isK ? Kbf : Qbf) + ((size_t)(bh << 12) + np) * 64;
#pragma unroll
  for (int ch = 0; ch < 8; ++ch) {
    *(bf16x8*)&dd[ch * 8] = *(bf16x8*)&ob0[ch * 8];
    *(bf16x8*)&dd[64 + ch * 8] = *(bf16x8*)&ob1[ch * 8];
  }
}

// ---------------- flash attention split-K v10: K-direct regs + dbuf LDS, 1 barrier/iter, ptr-bump ----------------
// grid 1024 = chunk*512 + bh*64 + nt; block 256 (4 waves).
__global__ __launch_bounds__(256) void attn_split_kernel(const __bf16* __restrict__ Qbf, const __bf16* __restrict__ Kbf,
                                                         const __bf16* __restrict__ Vbf, float* __restrict__ part) {
  __shared__ __align__(16) __bf16 Vc[2][48 * 72];   // Vc[buf][c][m]
  __shared__ __align__(16) __bf16 Pl[2][64 * 72];   // Pl[buf][n][m] (Pl[0] reused as Lred in epilogue)
  const int tid = threadIdx.x;
  const int lane = tid & 63;
  const int wv = tid >> 6;
  const int q4 = lane >> 4, l16 = lane & 15;
  const int bid = blockIdx.x;
  const int chunk = bid >> 9, rest = bid & 511;
  const int bh = rest >> 6, nt = rest & 63;
  const int n0 = nt * 64;
  const __bf16* Qg = Qbf + (size_t)bh * HW * 64;
  const __bf16* Kg = Kbf + (size_t)bh * HW * 64;
  const __bf16* Vg = Vbf + (size_t)bh * DH * HW;

  // Q fragments in registers (B-operand of S^T): qf[s][ks] = Q[n0+16s+l16][32ks+8q4 ..+7]
  bf16x8 qf[4][2];
#pragma unroll
  for (int s = 0; s < 4; ++s)
#pragma unroll
    for (int ks = 0; ks < 2; ++ks)
      qf[s][ks] = *(const bf16x8*)&Qg[((size_t)(n0 + 16 * s + l16)) * 64 + 32 * ks + 8 * q4];

  // K fragment pointers (per-wave rows) and V staging pointers; bump by one m-tile per iter.
  const int m0 = chunk * 2048;   // 32 m-tiles * 64
  const __bf16* kp0 = Kg + ((size_t)(m0 + 16 * wv + l16)) * 64 + 8 * q4;
  const __bf16* kp1 = kp0 + 32;
  const __bf16* vp0 = Vg + ((size_t)(tid >> 3)) * HW + m0 + (tid & 7) * 8;
  const __bf16* vp1 = Vg + ((size_t)((tid + 256) >> 3)) * HW + m0 + ((tid + 256) & 7) * 8;
  bf16x8 kf0 = *(const bf16x8*)kp0;
  bf16x8 kf1 = *(const bf16x8*)kp1;
  bf16x8 vreg[2];
  vreg[0] = *(const bf16x8*)vp0;
  if (tid < 128) vreg[1] = *(const bf16x8*)vp1;

  float lsub[4] = {0.f, 0.f, 0.f, 0.f};
  f32x4 oacc[3];
#pragma unroll
  for (int ct = 0; ct < 3; ++ct) oacc[ct] = (f32x4){0.f, 0.f, 0.f, 0.f};

  for (int it = 0; it < 32; ++it) {
    const int cur = it & 1;
    // write prefetched V regs -> LDS buffer `cur` (prior PV readers used buffer cur^1)
    *(bf16x8*)&Vc[cur][(tid >> 3) * 72 + (tid & 7) * 8] = vreg[0];
    if (tid < 128) {
      int i = tid + 256;
      *(bf16x8*)&Vc[cur][(i >> 3) * 72 + (i & 7) * 8] = vreg[1];
    }
    // issue next iteration's global loads (pointer bumps; final-iter over-read stays in workspace, unused)
    kp0 += 4096; kp1 += 4096; vp0 += 64; vp1 += 64;
    bf16x8 kn0 = *(const bf16x8*)kp0;
    bf16x8 kn1 = *(const bf16x8*)kp1;
    vreg[0] = *(const bf16x8*)vp0;
    if (tid < 128) vreg[1] = *(const bf16x8*)vp1;

    // S^T[m][n] = K·Q^T: pure-register MFMA
    f32x4 sacc[4];
#pragma unroll
    for (int s = 0; s < 4; ++s) sacc[s] = (f32x4){0.f, 0.f, 0.f, 0.f};
    __builtin_amdgcn_s_setprio(1);
#pragma unroll
    for (int s = 0; s < 4; ++s)
      sacc[s] = __builtin_amdgcn_mfma_f32_16x16x32_bf16(kf0, qf[s][0], sacc[s], 0, 0, 0);
#pragma unroll
    for (int s = 0; s < 4; ++s)
      sacc[s] = __builtin_amdgcn_mfma_f32_16x16x32_bf16(kf1, qf[s][1], sacc[s], 0, 0, 0);
    __builtin_amdgcn_s_setprio(0);

    // maxless softmax (log2e pre-folded into Q); raw v_exp; packed b64 P writes (m-contig)
#pragma unroll
    for (int s = 0; s < 4; ++s) {
      float p0 = exp2_fast(sacc[s][0]);
      float p1 = exp2_fast(sacc[s][1]);
      float p2 = exp2_fast(sacc[s][2]);
      float p3 = exp2_fast(sacc[s][3]);
      lsub[s] += (p0 + p1) + (p2 + p3);
      bf16x4 pk = { (__bf16)p0, (__bf16)p1, (__bf16)p2, (__bf16)p3 };
      *(bf16x4*)&Pl[cur][(16 * s + l16) * 72 + 16 * wv + 4 * q4] = pk;
    }
    __syncthreads();                     // publish Vc[cur] + Pl[cur] (the ONLY barrier per iter)

    // O[n][c] += P·V^T: wave owns n-strip 16wv
    __builtin_amdgcn_s_setprio(1);
#pragma unroll
    for (int ks = 0; ks < 2; ++ks) {
      bf16x8 pf = *(const bf16x8*)&Pl[cur][(16 * wv + l16) * 72 + 32 * ks + 8 * q4];
#pragma unroll
      for (int ct = 0; ct < 3; ++ct) {
        bf16x8 vf = *(const bf16x8*)&Vc[cur][(16 * ct + l16) * 72 + 32 * ks + 8 * q4];
        oacc[ct] = __builtin_amdgcn_mfma_f32_16x16x32_bf16(pf, vf, oacc[ct], 0, 0, 0);
      }
    }
    __builtin_amdgcn_s_setprio(0);
    kf0 = kn0; kf1 = kn1;
  }

  // epilogue
  __syncthreads();
  float* Lred = (float*)&Pl[0][0];
#pragma unroll
  for (int s = 0; s < 4; ++s) {
    float v = lsub[s];
    v += __shfl_xor(v, 16, 64);
    v += __shfl_xor(v, 32, 64);
    if (q4 == 0) Lred[wv * 64 + 16 * s + l16] = v;
  }
  __syncthreads();
  size_t pbase = (size_t)bid * 3136;
  if (tid < 64)
    part[pbase + 3072 + tid] = Lred[tid] + Lred[64 + tid] + Lred[128 + tid] + Lred[192 + tid];
#pragma unroll
  for (int ct = 0; ct < 3; ++ct)
#pragma unroll
    for (int r = 0; r < 4; ++r) {
      int n = 16 * wv + 4 * q4 + r;
      part[pbase + (size_t)n * 48 + 16 * ct + l16] = oacc[ct][r];
    }
}

extern "C" void kernel_launch(void* const* d_in, const int* in_sizes, int n_in,
                              void* d_out, int out_size, void* d_ws, size_t ws_size,
                              hipStream_t stream) {
  const float* x        = (const float*)d_in[0];
  const float* ln1_w    = (const float*)d_in[1];
  const float* ln1_b    = (const float*)d_in[2];
  const float* qkv_w    = (const float*)d_in[3];
  const float* qkv_b    = (const float*)d_in[4];
  const float* qkv_dw_w = (const float*)d_in[5];
  const float* qkv_dw_b = (const float*)d_in[6];
  const float* temperature = (const float*)d_in[7];
  const float* proj_w   = (const float*)d_in[8];
  const float* proj_b   = (const float*)d_in[9];
  const float* ln2_w    = (const float*)d_in[10];
  const float* ln2_b    = (const float*)d_in[11];
  const float* pin_w    = (const float*)d_in[12];
  const float* pin_b    = (const float*)d_in[13];
  const float* gdfn_dw_w = (const float*)d_in[14];
  const float* gdfn_dw_b = (const float*)d_in[15];
  const float* pout_w   = (const float*)d_in[16];
  const float* pout_b   = (const float*)d_in[17];
  float* out = (float*)d_out;
  float* ws = (float*)d_ws;

  // ---- workspace layout (float offsets) ----
  __bf16* wb_qkv  = (__bf16*)(ws + 0);          // 55296 f
  __bf16* wb_proj = (__bf16*)(ws + 55296);      // 18432 f
  __bf16* wb_pin  = (__bf16*)(ws + 73728);      // 97920 f
  __bf16* wb_pout = (__bf16*)(ws + 171648);     // 49152 f
  float* sc1 = ws + 220800;
  float* sh1 = ws + 221184;
  float* lnsum = ws + 221568;                   // 768 f (LN2 sum/sumsq; was sc2/sh2) -> ends 222336
  // region B @222336: Xt1/Xt2 overlap Qbf; Q/K/V bf16
  __bf16* Xt1 = (__bf16*)(ws + 222336);
  __bf16* Xt2 = (__bf16*)(ws + 222336);
  __bf16* Qbf = (__bf16*)(ws + 222336);         // 1,048,576 f
  __bf16* Kbf = (__bf16*)(ws + 1270912);        // 1,048,576 f
  __bf16* Vbf = (__bf16*)(ws + 2319488);        // 786,432 f -> ends 3,105,920
  // region C @3,105,920: qkvb bf16 -> later hid
  __bf16* qkvb   = (__bf16*)(ws + 3105920);
  __bf16* hid    = (__bf16*)(ws + 3105920);     // ends 7,283,840
  // region D @5,465,216: qdwb (dead before attn) then Opart (1024 blocks)
  __bf16* qdwb  = (__bf16*)(ws + 5465216);
  float*  Opart = ws + 5465216;                 // 1024*3136 = 3,211,264 f -> ends 8,676,480
  __bf16* gate  = (__bf16*)(ws + 7283840);      // 2,088,960 f (phase B, Opart dead)
  // total 11,887,744 f = 47.6 MB

  // ---- phase A ----
  wcvt_ln_kernel<<<1725 + 2 * DIMC, 256, 0, stream>>>(qkv_w, proj_w, pin_w, pout_w,
                                                      wb_qkv, wb_proj, wb_pin, wb_pout,
                                                      x, ln1_w, ln1_b, sc1, sh1, lnsum);
  ln_apply_t_kernel<<<dim3(64, 6, 2), 256, 0, stream>>>(x, sc1, sh1, Xt1);
  gemm_kernel<<<dim3(64, 9), 256, 0, stream>>>(wb_qkv, Xt1, qkv_b, nullptr, nullptr, qkvb,
                                               nullptr, nullptr, 576, 192, 1);
  dwconv_split_kernel<<<1152, 256, 0, stream>>>(qkvb, qkv_dw_w, qkv_dw_b, qdwb, Vbf);
  prep_qk_kernel<<<dim3(64, 2), 256, 0, stream>>>(qdwb, temperature, Qbf, Kbf);
  attn_split_kernel<<<1024, 256, 0, stream>>>(Qbf, Kbf, Vbf, Opart);
  gemm_kernel<<<dim3(64, 3), 256, 0, stream>>>(wb_proj, nullptr, proj_b, x, out, nullptr,
                                               Opart, lnsum, 192, 192, 4);   // + fused LN2 stats

  // ---- phase B ----
  ln_apply_t_sum_kernel<<<dim3(64, 6, 2), 256, 0, stream>>>(out, lnsum, ln2_w, ln2_b, Xt2);
  gemm_kernel<<<dim3(64, 16), 256, 0, stream>>>(wb_pin, Xt2, pin_b, nullptr, nullptr, hid,
                                                nullptr, nullptr, 1020, 192, 1);
  gdfn_dw_gate_kernel<<<2 * HIDC, 256, 0, stream>>>(hid, gdfn_dw_w, gdfn_dw_b, gate);
  gemm_kernel<<<dim3(64, 3), 256, 0, stream>>>(wb_pout, (const __bf16*)gate, pout_b, out, out, nullptr,
                                               nullptr, nullptr, 192, 512, 3);
}